// Round 5
// baseline (308.983 us; speedup 1.0000x reference)
//
#include <hip/hip_runtime.h>
#include <hip/hip_bf16.h>

// LQR-MPC: T=50, N=12, M=4, NSC=16, NB=8192.
// 8 elements per 64-thread wave: lane = (c = tid&15, g = tid>>4); group g owns
// elements bA = blk*8+g and bB = bA+4 (two interleaved sets -> ILP-2, and the
// 48 sF broadcast reads per step feed BOTH sets). Single-wave blocks: all
// cross-lane comm is intra-wave, DS ops execute in order -> wave_barrier()
// (compiler fence, 0 cycles) replaces __syncthreads (no vmcnt/lgkmcnt drains).
// Gains to d_ws (f32/bf16 by ws_size) or LDS fallback. Forward: DPP row_ror
// u-reduction (VALU, no DS), x broadcast via 4 LDS ops.
// Vn = Qxx + Qxu*K exactly (K^T Qux + K^T Quu K cancels).
#define TT 50
#define NBB 8192
#define QS  20    // Qt col stride (floats) within element block
#define QTE 88    // Qt per-elem stride (88%32=24 -> distinct start banks)
#define VES 152   // V per-elem stride

__device__ __forceinline__ unsigned short f2bf(float f) {
  unsigned int u = __float_as_uint(f);
  u = (u + 0x7FFFu + ((u >> 16) & 1u)) >> 16;   // RNE
  return (unsigned short)u;
}
__device__ __forceinline__ float bf2f(unsigned short h) {
  return __uint_as_float(((unsigned int)h) << 16);
}
__device__ __forceinline__ float rrsum16(float v) {
  int t;
  t = __builtin_amdgcn_update_dpp(0, __float_as_int(v), 0x128, 0xF, 0xF, true); v += __int_as_float(t); // ror:8
  t = __builtin_amdgcn_update_dpp(0, __float_as_int(v), 0x124, 0xF, 0xF, true); v += __int_as_float(t); // ror:4
  t = __builtin_amdgcn_update_dpp(0, __float_as_int(v), 0x122, 0xF, 0xF, true); v += __int_as_float(t); // ror:2
  t = __builtin_amdgcn_update_dpp(0, __float_as_int(v), 0x121, 0xF, 0xF, true); v += __int_as_float(t); // ror:1
  return v;
}

// Branchless partial-pivot LU on [Quu | r1 | r2]; returns s1 = -Quu^-1 r1, s2 = -Quu^-1 r2
__device__ __forceinline__ void lu46(const float4 q0, const float4 q1, const float4 q2, const float4 q3,
                                     const float4 r1, const float4 r2, float4& s1, float4& s2) {
  float M[4][6];
  M[0][0]=q0.x; M[1][0]=q0.y; M[2][0]=q0.z; M[3][0]=q0.w;
  M[0][1]=q1.x; M[1][1]=q1.y; M[2][1]=q1.z; M[3][1]=q1.w;
  M[0][2]=q2.x; M[1][2]=q2.y; M[2][2]=q2.z; M[3][2]=q2.w;
  M[0][3]=q3.x; M[1][3]=q3.y; M[2][3]=q3.z; M[3][3]=q3.w;
  M[0][4]=r1.x; M[1][4]=r1.y; M[2][4]=r1.z; M[3][4]=r1.w;
  M[0][5]=r2.x; M[1][5]=r2.y; M[2][5]=r2.z; M[3][5]=r2.w;
  #pragma unroll
  for (int k = 0; k < 4; ++k) {
    #pragma unroll
    for (int i = k+1; i < 4; ++i) {
      const bool sw = fabsf(M[i][k]) > fabsf(M[k][k]);
      #pragma unroll
      for (int j = 0; j < 6; ++j) {
        const float a_ = M[k][j], b_ = M[i][j];
        M[k][j] = sw ? b_ : a_;
        M[i][j] = sw ? a_ : b_;
      }
    }
    const float inv = __builtin_amdgcn_rcpf(M[k][k]);
    #pragma unroll
    for (int i = k+1; i < 4; ++i) {
      const float f = M[i][k] * inv;
      #pragma unroll
      for (int j = k+1; j < 6; ++j) M[i][j] = fmaf(-f, M[k][j], M[i][j]);
    }
  }
  const float i33 = __builtin_amdgcn_rcpf(M[3][3]);
  const float i22 = __builtin_amdgcn_rcpf(M[2][2]);
  const float i11 = __builtin_amdgcn_rcpf(M[1][1]);
  const float i00 = __builtin_amdgcn_rcpf(M[0][0]);
  const float a3 = M[3][4]*i33;
  const float b3 = M[3][5]*i33;
  const float a2 = fmaf(-M[2][3],a3,M[2][4])*i22;
  const float b2 = fmaf(-M[2][3],b3,M[2][5])*i22;
  const float a1 = fmaf(-M[1][3],a3,fmaf(-M[1][2],a2,M[1][4]))*i11;
  const float b1 = fmaf(-M[1][3],b3,fmaf(-M[1][2],b2,M[1][5]))*i11;
  const float a0 = fmaf(-M[0][3],a3,fmaf(-M[0][2],a2,fmaf(-M[0][1],a1,M[0][4])))*i00;
  const float b0 = fmaf(-M[0][3],b3,fmaf(-M[0][2],b2,fmaf(-M[0][1],b1,M[0][5])))*i00;
  s1 = make_float4(-a0,-a1,-a2,-a3);
  s2 = make_float4(-b0,-b1,-b2,-b3);
}

// MODE: 0 = f32 gains in d_ws, 1 = bf16 gains in d_ws, 2 = gains in LDS
template <int MODE>
__global__ __launch_bounds__(64, 2) void mpc_kernel(
    const void* __restrict__ x_init, const void* __restrict__ Qm,
    const void* __restrict__ pm, const void* __restrict__ Am,
    const void* __restrict__ Bm, void* __restrict__ outv,
    void* __restrict__ wsv)
{
  __shared__ float sF[192];        // col-major: sF[a*12+i] = F[i][a], F=[A|B] 12x16
  __shared__ float sFr[320];       // row-major, stride 20: sFr[i*20+a]
  __shared__ float sV[8*VES];      // per-elem V col-major 12x12
  __shared__ float sQt[8*QTE];     // per-elem Qt cols 12..15 only, col stride QS
  __shared__ float sqt[8*20];      // per-elem qu (qt rows 12..15)
  __shared__ float svv[8*20];      // per-elem v (12)
  __shared__ float sx[8*20];       // per-elem x broadcast (fwd)
  __shared__ float sG[(MODE == 2) ? (8*2600) : 4];

  const int tid = threadIdx.x;
  const int c = tid & 15;
  const int g = tid >> 4;
  const int bA = (int)blockIdx.x * 8 + g;
  const int bB = bA + 4;
  const int eA = g, eB = g + 4;

  // ---- runtime dtype detection (wave-uniform) ----
  bool isf32;
  {
    const unsigned int* aw = (const unsigned int*)Am;
    int insane = 0;
    #pragma unroll 4
    for (int k = 0; k < 72; ++k) {
      const unsigned int w = aw[k];
      const unsigned short h0 = (unsigned short)(w & 0xFFFFu);
      const unsigned short h1 = (unsigned short)(w >> 16);
      const int e0 = (h0 >> 7) & 0xFF, e1 = (h1 >> 7) & 0xFF;
      insane += (((h0 & 0x7FFF) != 0) && (e0 < 107 || e0 > 132)) ? 1 : 0;
      insane += (((h1 & 0x7FFF) != 0) && (e1 < 107 || e1 > 132)) ? 1 : 0;
    }
    isf32 = (insane > 8);
  }

  const float* const xf = (const float*)x_init;
  const float* const Qf = (const float*)Qm;
  const float* const pf = (const float*)pm;
  const float* const Af = (const float*)Am;
  const float* const Bf = (const float*)Bm;
  const unsigned short* const xh = (const unsigned short*)x_init;
  const unsigned short* const Qh = (const unsigned short*)Qm;
  const unsigned short* const ph = (const unsigned short*)pm;
  const unsigned short* const Ah = (const unsigned short*)Am;
  const unsigned short* const Bh = (const unsigned short*)Bm;

  // ---- stage F; zero V, v ----
  for (int idx = tid; idx < 320; idx += 64) {
    const int i_ = idx / 20, a_ = idx - i_ * 20;
    float fv = 0.f;
    if (i_ < 12 && a_ < 16) {
      if (a_ < 12) fv = isf32 ? Af[i_*12 + a_] : bf2f(Ah[i_*12 + a_]);
      else         fv = isf32 ? Bf[i_*4 + (a_-12)] : bf2f(Bh[i_*4 + (a_-12)]);
    }
    sFr[idx] = fv;
  }
  for (int idx = tid; idx < 192; idx += 64) {
    const int a_ = idx / 12, i_ = idx - a_ * 12;
    float fv;
    if (a_ < 12) fv = isf32 ? Af[i_*12 + a_] : bf2f(Ah[i_*12 + a_]);
    else         fv = isf32 ? Bf[i_*4 + (a_-12)] : bf2f(Bh[i_*4 + (a_-12)]);
    sF[idx] = fv;
  }
  for (int idx = tid; idx < 8*VES; idx += 64) sV[idx] = 0.f;
  for (int idx = tid; idx < 8*20; idx += 64) svv[idx] = 0.f;
  __syncthreads();

  float Fc[12];
  #pragma unroll
  for (int i = 0; i < 12; ++i) Fc[i] = sF[c*12 + i];
  const float QdA = isf32 ? Qf[bA*16 + c] : bf2f(Qh[bA*16 + c]);
  const float pcA = isf32 ? pf[bA*16 + c] : bf2f(ph[bA*16 + c]);
  const float QdB = isf32 ? Qf[bB*16 + c] : bf2f(Qh[bB*16 + c]);
  const float pcB = isf32 ? pf[bB*16 + c] : bf2f(ph[bB*16 + c]);

  float* const vbA  = &sV[eA*VES];
  float* const vbB  = &sV[eB*VES];
  float* const qtbA = &sQt[eA*QTE];
  float* const qtbB = &sQt[eB*QTE];
  float* const quA  = &sqt[eA*20];
  float* const quB  = &sqt[eB*20];
  float* const vvA  = &svv[eA*20];
  float* const vvB  = &svv[eB*20];
  float* const sxA  = &sx[eA*20];
  float* const sxB  = &sx[eB*20];
  float* const gbA  = (MODE == 2) ? &sG[eA*2600] : nullptr;
  float* const gbB  = (MODE == 2) ? &sG[eB*2600] : nullptr;

  float* const wsf = (float*)wsv;
  unsigned short* const wsh = (unsigned short*)wsv;

  // ----------------- backward Riccati pass -----------------
  for (int it = 0; it < TT; ++it) {
    // W_s = V_s * F[:,c]
    float WA[12], WB[12];
    #pragma unroll
    for (int i = 0; i < 12; ++i) { WA[i] = 0.f; WB[i] = 0.f; }
    #pragma unroll
    for (int j = 0; j < 12; ++j) {
      const float fj = Fc[j];
      const float4 a0 = *(const float4*)(vbA + j*12);
      const float4 a1 = *(const float4*)(vbA + j*12 + 4);
      const float4 a2 = *(const float4*)(vbA + j*12 + 8);
      const float4 b0 = *(const float4*)(vbB + j*12);
      const float4 b1 = *(const float4*)(vbB + j*12 + 4);
      const float4 b2 = *(const float4*)(vbB + j*12 + 8);
      WA[0]=fmaf(a0.x,fj,WA[0]); WA[1]=fmaf(a0.y,fj,WA[1]); WA[2]=fmaf(a0.z,fj,WA[2]); WA[3]=fmaf(a0.w,fj,WA[3]);
      WA[4]=fmaf(a1.x,fj,WA[4]); WA[5]=fmaf(a1.y,fj,WA[5]); WA[6]=fmaf(a1.z,fj,WA[6]); WA[7]=fmaf(a1.w,fj,WA[7]);
      WA[8]=fmaf(a2.x,fj,WA[8]); WA[9]=fmaf(a2.y,fj,WA[9]); WA[10]=fmaf(a2.z,fj,WA[10]); WA[11]=fmaf(a2.w,fj,WA[11]);
      WB[0]=fmaf(b0.x,fj,WB[0]); WB[1]=fmaf(b0.y,fj,WB[1]); WB[2]=fmaf(b0.z,fj,WB[2]); WB[3]=fmaf(b0.w,fj,WB[3]);
      WB[4]=fmaf(b1.x,fj,WB[4]); WB[5]=fmaf(b1.y,fj,WB[5]); WB[6]=fmaf(b1.z,fj,WB[6]); WB[7]=fmaf(b1.w,fj,WB[7]);
      WB[8]=fmaf(b2.x,fj,WB[8]); WB[9]=fmaf(b2.y,fj,WB[9]); WB[10]=fmaf(b2.z,fj,WB[10]); WB[11]=fmaf(b2.w,fj,WB[11]);
    }
    // qt[c] = p[c] + F[:,c].v
    float qtsA = pcA, qtsB = pcB;
    {
      const float4 va0 = *(const float4*)(vvA);
      const float4 va1 = *(const float4*)(vvA + 4);
      const float4 va2 = *(const float4*)(vvA + 8);
      const float4 vb0 = *(const float4*)(vvB);
      const float4 vb1 = *(const float4*)(vvB + 4);
      const float4 vb2 = *(const float4*)(vvB + 8);
      qtsA = fmaf(Fc[0],va0.x,qtsA); qtsA = fmaf(Fc[1],va0.y,qtsA); qtsA = fmaf(Fc[2],va0.z,qtsA); qtsA = fmaf(Fc[3],va0.w,qtsA);
      qtsA = fmaf(Fc[4],va1.x,qtsA); qtsA = fmaf(Fc[5],va1.y,qtsA); qtsA = fmaf(Fc[6],va1.z,qtsA); qtsA = fmaf(Fc[7],va1.w,qtsA);
      qtsA = fmaf(Fc[8],va2.x,qtsA); qtsA = fmaf(Fc[9],va2.y,qtsA); qtsA = fmaf(Fc[10],va2.z,qtsA); qtsA = fmaf(Fc[11],va2.w,qtsA);
      qtsB = fmaf(Fc[0],vb0.x,qtsB); qtsB = fmaf(Fc[1],vb0.y,qtsB); qtsB = fmaf(Fc[2],vb0.z,qtsB); qtsB = fmaf(Fc[3],vb0.w,qtsB);
      qtsB = fmaf(Fc[4],vb1.x,qtsB); qtsB = fmaf(Fc[5],vb1.y,qtsB); qtsB = fmaf(Fc[6],vb1.z,qtsB); qtsB = fmaf(Fc[7],vb1.w,qtsB);
      qtsB = fmaf(Fc[8],vb2.x,qtsB); qtsB = fmaf(Fc[9],vb2.y,qtsB); qtsB = fmaf(Fc[10],vb2.z,qtsB); qtsB = fmaf(Fc[11],vb2.w,qtsB);
    }
    // Qt column c for both sets; each F column read once
    float qtcA[16], qtcB[16];
    #pragma unroll
    for (int a = 0; a < 16; ++a) {
      const float4 f0 = *(const float4*)(sF + a*12);
      const float4 f1 = *(const float4*)(sF + a*12 + 4);
      const float4 f2 = *(const float4*)(sF + a*12 + 8);
      float accA = f0.x*WA[0];
      accA = fmaf(f0.y,WA[1],accA); accA = fmaf(f0.z,WA[2],accA); accA = fmaf(f0.w,WA[3],accA);
      accA = fmaf(f1.x,WA[4],accA); accA = fmaf(f1.y,WA[5],accA); accA = fmaf(f1.z,WA[6],accA); accA = fmaf(f1.w,WA[7],accA);
      accA = fmaf(f2.x,WA[8],accA); accA = fmaf(f2.y,WA[9],accA); accA = fmaf(f2.z,WA[10],accA); accA = fmaf(f2.w,WA[11],accA);
      float accB = f0.x*WB[0];
      accB = fmaf(f0.y,WB[1],accB); accB = fmaf(f0.z,WB[2],accB); accB = fmaf(f0.w,WB[3],accB);
      accB = fmaf(f1.x,WB[4],accB); accB = fmaf(f1.y,WB[5],accB); accB = fmaf(f1.z,WB[6],accB); accB = fmaf(f1.w,WB[7],accB);
      accB = fmaf(f2.x,WB[8],accB); accB = fmaf(f2.y,WB[9],accB); accB = fmaf(f2.z,WB[10],accB); accB = fmaf(f2.w,WB[11],accB);
      if (a == c) { accA += QdA; accB += QdB; }
      qtcA[a] = accA; qtcB[a] = accB;
    }
    // only cols 12..15 are read cross-lane
    if (c >= 12) {
      float* qa = qtbA + (c-12)*QS;
      *(float4*)(qa     ) = make_float4(qtcA[0],qtcA[1],qtcA[2],qtcA[3]);
      *(float4*)(qa +  4) = make_float4(qtcA[4],qtcA[5],qtcA[6],qtcA[7]);
      *(float4*)(qa +  8) = make_float4(qtcA[8],qtcA[9],qtcA[10],qtcA[11]);
      *(float4*)(qa + 12) = make_float4(qtcA[12],qtcA[13],qtcA[14],qtcA[15]);
      float* qb = qtbB + (c-12)*QS;
      *(float4*)(qb     ) = make_float4(qtcB[0],qtcB[1],qtcB[2],qtcB[3]);
      *(float4*)(qb +  4) = make_float4(qtcB[4],qtcB[5],qtcB[6],qtcB[7]);
      *(float4*)(qb +  8) = make_float4(qtcB[8],qtcB[9],qtcB[10],qtcB[11]);
      *(float4*)(qb + 12) = make_float4(qtcB[12],qtcB[13],qtcB[14],qtcB[15]);
      quA[c-12] = qtsA;
      quB[c-12] = qtsB;
    }
    __builtin_amdgcn_wave_barrier();   // single-wave block: DS in-order; fence compiler only

    // Quu + qu broadcast; LU per set
    const float4 qa0 = *(const float4*)(qtbA + 0*QS + 12);
    const float4 qa1 = *(const float4*)(qtbA + 1*QS + 12);
    const float4 qa2 = *(const float4*)(qtbA + 2*QS + 12);
    const float4 qa3 = *(const float4*)(qtbA + 3*QS + 12);
    const float4 quAv = *(const float4*)(quA);
    const float4 qb0 = *(const float4*)(qtbB + 0*QS + 12);
    const float4 qb1 = *(const float4*)(qtbB + 1*QS + 12);
    const float4 qb2 = *(const float4*)(qtbB + 2*QS + 12);
    const float4 qb3 = *(const float4*)(qtbB + 3*QS + 12);
    const float4 quBv = *(const float4*)(quB);

    float4 KcA, kfA, KcB, kfB;
    lu46(qa0,qa1,qa2,qa3, make_float4(qtcA[12],qtcA[13],qtcA[14],qtcA[15]), quAv, KcA, kfA);
    lu46(qb0,qb1,qb2,qb3, make_float4(qtcB[12],qtcB[13],qtcB[14],qtcB[15]), quBv, KcB, kfB);

    // store gains: [t][b][col 0..12][4], col 12 = kff; t = TT-1-it
    if (c < 13) {
      float4 gwA, gwB;
      gwA.x = (c < 12) ? KcA.x : kfA.x; gwA.y = (c < 12) ? KcA.y : kfA.y;
      gwA.z = (c < 12) ? KcA.z : kfA.z; gwA.w = (c < 12) ? KcA.w : kfA.w;
      gwB.x = (c < 12) ? KcB.x : kfB.x; gwB.y = (c < 12) ? KcB.y : kfB.y;
      gwB.z = (c < 12) ? KcB.z : kfB.z; gwB.w = (c < 12) ? KcB.w : kfB.w;
      if (MODE == 2) {
        *(float4*)(gbA + (TT-1-it)*52 + c*4) = gwA;
        *(float4*)(gbB + (TT-1-it)*52 + c*4) = gwB;
      } else {
        const size_t offA = ((size_t)(TT-1-it)*NBB + bA)*52 + (size_t)c*4;
        const size_t offB = ((size_t)(TT-1-it)*NBB + bB)*52 + (size_t)c*4;
        if (MODE == 1) {
          ushort4 usA, usB;
          usA.x = f2bf(gwA.x); usA.y = f2bf(gwA.y); usA.z = f2bf(gwA.z); usA.w = f2bf(gwA.w);
          usB.x = f2bf(gwB.x); usB.y = f2bf(gwB.y); usB.z = f2bf(gwB.z); usB.w = f2bf(gwB.w);
          *(ushort4*)(wsh + offA) = usA;
          *(ushort4*)(wsh + offB) = usB;
        } else {
          *(float4*)(wsf + offA) = gwA;
          *(float4*)(wsf + offB) = gwB;
        }
      }
    }

    // Vn[:,c] = Qxx[:,c] + Qxu * K[:,c]; vn[c] = qt[c] + Qxu[c,:].kff
    if (c < 12) {
      float VnA[12], VnB[12];
      #pragma unroll
      for (int i = 0; i < 12; ++i) { VnA[i] = qtcA[i]; VnB[i] = qtcB[i]; }
      #pragma unroll
      for (int u = 0; u < 4; ++u) {
        const float kuA = (u==0)?KcA.x:((u==1)?KcA.y:((u==2)?KcA.z:KcA.w));
        const float kuB = (u==0)?KcB.x:((u==1)?KcB.y:((u==2)?KcB.z:KcB.w));
        const float4 xa0 = *(const float4*)(qtbA + u*QS);
        const float4 xa1 = *(const float4*)(qtbA + u*QS + 4);
        const float4 xa2 = *(const float4*)(qtbA + u*QS + 8);
        const float4 xb0 = *(const float4*)(qtbB + u*QS);
        const float4 xb1 = *(const float4*)(qtbB + u*QS + 4);
        const float4 xb2 = *(const float4*)(qtbB + u*QS + 8);
        VnA[0]=fmaf(xa0.x,kuA,VnA[0]); VnA[1]=fmaf(xa0.y,kuA,VnA[1]); VnA[2]=fmaf(xa0.z,kuA,VnA[2]); VnA[3]=fmaf(xa0.w,kuA,VnA[3]);
        VnA[4]=fmaf(xa1.x,kuA,VnA[4]); VnA[5]=fmaf(xa1.y,kuA,VnA[5]); VnA[6]=fmaf(xa1.z,kuA,VnA[6]); VnA[7]=fmaf(xa1.w,kuA,VnA[7]);
        VnA[8]=fmaf(xa2.x,kuA,VnA[8]); VnA[9]=fmaf(xa2.y,kuA,VnA[9]); VnA[10]=fmaf(xa2.z,kuA,VnA[10]); VnA[11]=fmaf(xa2.w,kuA,VnA[11]);
        VnB[0]=fmaf(xb0.x,kuB,VnB[0]); VnB[1]=fmaf(xb0.y,kuB,VnB[1]); VnB[2]=fmaf(xb0.z,kuB,VnB[2]); VnB[3]=fmaf(xb0.w,kuB,VnB[3]);
        VnB[4]=fmaf(xb1.x,kuB,VnB[4]); VnB[5]=fmaf(xb1.y,kuB,VnB[5]); VnB[6]=fmaf(xb1.z,kuB,VnB[6]); VnB[7]=fmaf(xb1.w,kuB,VnB[7]);
        VnB[8]=fmaf(xb2.x,kuB,VnB[8]); VnB[9]=fmaf(xb2.y,kuB,VnB[9]); VnB[10]=fmaf(xb2.z,kuB,VnB[10]); VnB[11]=fmaf(xb2.w,kuB,VnB[11]);
      }
      float vnA = qtsA, vnB = qtsB;
      vnA = fmaf(qtcA[12],kfA.x,vnA); vnA = fmaf(qtcA[13],kfA.y,vnA);
      vnA = fmaf(qtcA[14],kfA.z,vnA); vnA = fmaf(qtcA[15],kfA.w,vnA);
      vnB = fmaf(qtcB[12],kfB.x,vnB); vnB = fmaf(qtcB[13],kfB.y,vnB);
      vnB = fmaf(qtcB[14],kfB.z,vnB); vnB = fmaf(qtcB[15],kfB.w,vnB);
      *(float4*)(vbA + c*12    ) = make_float4(VnA[0],VnA[1],VnA[2],VnA[3]);
      *(float4*)(vbA + c*12 + 4) = make_float4(VnA[4],VnA[5],VnA[6],VnA[7]);
      *(float4*)(vbA + c*12 + 8) = make_float4(VnA[8],VnA[9],VnA[10],VnA[11]);
      *(float4*)(vbB + c*12    ) = make_float4(VnB[0],VnB[1],VnB[2],VnB[3]);
      *(float4*)(vbB + c*12 + 4) = make_float4(VnB[4],VnB[5],VnB[6],VnB[7]);
      *(float4*)(vbB + c*12 + 8) = make_float4(VnB[8],VnB[9],VnB[10],VnB[11]);
      vvA[c] = vnA;
      vvB[c] = vnB;
    }
    __builtin_amdgcn_wave_barrier();
  }

  // ----------------- forward rollout -----------------
  if (MODE != 2) __threadfence();  // drain own gain stores before reading them back

  float xcA = 0.f, xcB = 0.f;
  if (c < 12) {
    xcA = isf32 ? xf[bA*12 + c] : bf2f(xh[bA*12 + c]);
    xcB = isf32 ? xf[bB*12 + c] : bf2f(xh[bB*12 + c]);
  }

  float* const outf = (float*)outv;
  unsigned short* const outh = (unsigned short*)outv;

  // gain load helper
  auto loadg = [&](int t, int b, float* gb) -> float4 {
    if (c >= 13) return make_float4(0.f,0.f,0.f,0.f);
    if (MODE == 2) return *(const float4*)(gb + t*52 + c*4);
    const size_t off = ((size_t)t*NBB + b)*52 + (size_t)c*4;
    if (MODE == 1) {
      const ushort4 us = *(const ushort4*)(wsh + off);
      return make_float4(bf2f(us.x),bf2f(us.y),bf2f(us.z),bf2f(us.w));
    }
    return *(const float4*)(wsf + off);
  };

  float4 gA = loadg(0, bA, gbA);
  float4 gB = loadg(0, bB, gbB);

  for (int t = 0; t < TT; ++t) {
    // broadcast x via LDS (intra-wave, in-order DS)
    if (c < 12) { sxA[c] = xcA; sxB[c] = xcB; }
    __builtin_amdgcn_wave_barrier();
    const float4 xa0 = *(const float4*)(sxA);
    const float4 xa1 = *(const float4*)(sxA + 4);
    const float4 xa2 = *(const float4*)(sxA + 8);
    const float4 xb0 = *(const float4*)(sxB);
    const float4 xb1 = *(const float4*)(sxB + 4);
    const float4 xb2 = *(const float4*)(sxB + 8);

    // u = sum_c K[:,c]*x[c] + kff via DPP row_ror reduction (c>=13 lanes have g=0)
    const float sA = (c < 12) ? xcA : 1.0f;
    const float sB = (c < 12) ? xcB : 1.0f;
    const float u0A = rrsum16(gA.x*sA), u1A = rrsum16(gA.y*sA), u2A = rrsum16(gA.z*sA), u3A = rrsum16(gA.w*sA);
    const float u0B = rrsum16(gB.x*sB), u1B = rrsum16(gB.y*sB), u2B = rrsum16(gB.z*sB), u3B = rrsum16(gB.w*sB);

    if (c == 0) {
      const size_t oA = ((size_t)t*NBB + bA)*4;
      const size_t oB = ((size_t)t*NBB + bB)*4;
      if (isf32) {
        *(float4*)(outf + oA) = make_float4(u0A,u1A,u2A,u3A);
        *(float4*)(outf + oB) = make_float4(u0B,u1B,u2B,u3B);
      } else {
        ushort4 usA, usB;
        usA.x = f2bf(u0A); usA.y = f2bf(u1A); usA.z = f2bf(u2A); usA.w = f2bf(u3A);
        usB.x = f2bf(u0B); usB.y = f2bf(u1B); usB.z = f2bf(u2B); usB.w = f2bf(u3B);
        *(ushort4*)(outh + oA) = usA;
        *(ushort4*)(outh + oB) = usB;
      }
    }

    // prefetch next gains while x-update computes
    float4 gAn = make_float4(0,0,0,0), gBn = make_float4(0,0,0,0);
    if (t + 1 < TT) { gAn = loadg(t+1, bA, gbA); gBn = loadg(t+1, bB, gbB); }

    // x'[c] = F[c,:] . [x;u] — F rows shared across both sets
    const float4 fr0 = *(const float4*)(sFr + c*20);
    const float4 fr1 = *(const float4*)(sFr + c*20 + 4);
    const float4 fr2 = *(const float4*)(sFr + c*20 + 8);
    const float4 frB = *(const float4*)(sFr + c*20 + 12);
    float xpA = fr0.x*xa0.x;
    xpA = fmaf(fr0.y,xa0.y,xpA); xpA = fmaf(fr0.z,xa0.z,xpA); xpA = fmaf(fr0.w,xa0.w,xpA);
    xpA = fmaf(fr1.x,xa1.x,xpA); xpA = fmaf(fr1.y,xa1.y,xpA); xpA = fmaf(fr1.z,xa1.z,xpA); xpA = fmaf(fr1.w,xa1.w,xpA);
    xpA = fmaf(fr2.x,xa2.x,xpA); xpA = fmaf(fr2.y,xa2.y,xpA); xpA = fmaf(fr2.z,xa2.z,xpA); xpA = fmaf(fr2.w,xa2.w,xpA);
    xpA = fmaf(frB.x,u0A,xpA); xpA = fmaf(frB.y,u1A,xpA); xpA = fmaf(frB.z,u2A,xpA); xpA = fmaf(frB.w,u3A,xpA);
    float xpB = fr0.x*xb0.x;
    xpB = fmaf(fr0.y,xb0.y,xpB); xpB = fmaf(fr0.z,xb0.z,xpB); xpB = fmaf(fr0.w,xb0.w,xpB);
    xpB = fmaf(fr1.x,xb1.x,xpB); xpB = fmaf(fr1.y,xb1.y,xpB); xpB = fmaf(fr1.z,xb1.z,xpB); xpB = fmaf(fr1.w,xb1.w,xpB);
    xpB = fmaf(fr2.x,xb2.x,xpB); xpB = fmaf(fr2.y,xb2.y,xpB); xpB = fmaf(fr2.z,xb2.z,xpB); xpB = fmaf(fr2.w,xb2.w,xpB);
    xpB = fmaf(frB.x,u0B,xpB); xpB = fmaf(frB.y,u1B,xpB); xpB = fmaf(frB.z,u2B,xpB); xpB = fmaf(frB.w,u3B,xpB);
    xcA = xpA; xcB = xpB;
    gA = gAn; gB = gBn;
  }
}

extern "C" void kernel_launch(void* const* d_in, const int* in_sizes, int n_in,
                              void* d_out, int out_size, void* d_ws, size_t ws_size,
                              hipStream_t stream) {
  (void)in_sizes; (void)n_in; (void)out_size;
  const size_t needF = (size_t)TT * NBB * 52 * sizeof(float);          // 85.2 MB
  const size_t needH = (size_t)TT * NBB * 52 * sizeof(unsigned short); // 42.6 MB
  dim3 grid(NBB / 8), block(64);
  if (d_ws != nullptr && ws_size >= needF) {
    mpc_kernel<0><<<grid, block, 0, stream>>>(d_in[0], d_in[1], d_in[2], d_in[3], d_in[4], d_out, d_ws);
  } else if (d_ws != nullptr && ws_size >= needH) {
    mpc_kernel<1><<<grid, block, 0, stream>>>(d_in[0], d_in[1], d_in[2], d_in[3], d_in[4], d_out, d_ws);
  } else {
    mpc_kernel<2><<<grid, block, 0, stream>>>(d_in[0], d_in[1], d_in[2], d_in[3], d_in[4], d_out, d_ws);
  }
}

// Round 6
// 296.968 us; speedup vs baseline: 1.0405x; 1.0405x over previous
//
#include <hip/hip_runtime.h>
#include <hip/hip_bf16.h>

// LQR-MPC: T=50, N=12, M=4, NSC=16, NB=8192.
// 4 elements per 64-thread wave (c = tid&15 owns column c, g = tid>>4 owns
// element blk*4+g) -> 2048 waves = 8/CU for latency hiding. Single-wave
// blocks: DS ops in-order within a wave -> wave_barrier() (compiler-only
// fence) instead of __syncthreads. qtc inner product reads F ROWS from
// global A/B with wave-uniform addresses -> s_load (scalar path, off the
// DS pipe); opaque SGPR zero per step blocks LICM hoisting. Only Qt cols
// 12..15 round-trip LDS. Gains to d_ws (f32/bf16) or LDS fallback.
// Forward: DPP row_ror u-reduction (VALU-only), x broadcast via LDS.
// Vn = Qxx + Qxu*K exactly (K^T Qux + K^T Quu K cancels).
#define TT 50
#define NBB 8192
#define QS  20    // Qt col stride (floats)
#define QTE 88    // Qt per-elem stride (88%32=24 -> distinct start banks)
#define VES 152   // V per-elem stride

__device__ __forceinline__ unsigned short f2bf(float f) {
  unsigned int u = __float_as_uint(f);
  u = (u + 0x7FFFu + ((u >> 16) & 1u)) >> 16;   // RNE
  return (unsigned short)u;
}
__device__ __forceinline__ float bf2f(unsigned short h) {
  return __uint_as_float(((unsigned int)h) << 16);
}
__device__ __forceinline__ float rrsum16(float v) {
  int t;
  t = __builtin_amdgcn_update_dpp(0, __float_as_int(v), 0x128, 0xF, 0xF, true); v += __int_as_float(t); // ror:8
  t = __builtin_amdgcn_update_dpp(0, __float_as_int(v), 0x124, 0xF, 0xF, true); v += __int_as_float(t); // ror:4
  t = __builtin_amdgcn_update_dpp(0, __float_as_int(v), 0x122, 0xF, 0xF, true); v += __int_as_float(t); // ror:2
  t = __builtin_amdgcn_update_dpp(0, __float_as_int(v), 0x121, 0xF, 0xF, true); v += __int_as_float(t); // ror:1
  return v;
}

// Branchless partial-pivot LU on [Quu | r1 | r2]; s1 = -Quu^-1 r1, s2 = -Quu^-1 r2
__device__ __forceinline__ void lu46(const float4 q0, const float4 q1, const float4 q2, const float4 q3,
                                     const float4 r1, const float4 r2, float4& s1, float4& s2) {
  float M[4][6];
  M[0][0]=q0.x; M[1][0]=q0.y; M[2][0]=q0.z; M[3][0]=q0.w;
  M[0][1]=q1.x; M[1][1]=q1.y; M[2][1]=q1.z; M[3][1]=q1.w;
  M[0][2]=q2.x; M[1][2]=q2.y; M[2][2]=q2.z; M[3][2]=q2.w;
  M[0][3]=q3.x; M[1][3]=q3.y; M[2][3]=q3.z; M[3][3]=q3.w;
  M[0][4]=r1.x; M[1][4]=r1.y; M[2][4]=r1.z; M[3][4]=r1.w;
  M[0][5]=r2.x; M[1][5]=r2.y; M[2][5]=r2.z; M[3][5]=r2.w;
  #pragma unroll
  for (int k = 0; k < 4; ++k) {
    #pragma unroll
    for (int i = k+1; i < 4; ++i) {
      const bool sw = fabsf(M[i][k]) > fabsf(M[k][k]);
      #pragma unroll
      for (int j = 0; j < 6; ++j) {
        const float a_ = M[k][j], b_ = M[i][j];
        M[k][j] = sw ? b_ : a_;
        M[i][j] = sw ? a_ : b_;
      }
    }
    const float inv = __builtin_amdgcn_rcpf(M[k][k]);
    #pragma unroll
    for (int i = k+1; i < 4; ++i) {
      const float f = M[i][k] * inv;
      #pragma unroll
      for (int j = k+1; j < 6; ++j) M[i][j] = fmaf(-f, M[k][j], M[i][j]);
    }
  }
  const float i33 = __builtin_amdgcn_rcpf(M[3][3]);
  const float i22 = __builtin_amdgcn_rcpf(M[2][2]);
  const float i11 = __builtin_amdgcn_rcpf(M[1][1]);
  const float i00 = __builtin_amdgcn_rcpf(M[0][0]);
  const float a3 = M[3][4]*i33;
  const float b3 = M[3][5]*i33;
  const float a2 = fmaf(-M[2][3],a3,M[2][4])*i22;
  const float b2 = fmaf(-M[2][3],b3,M[2][5])*i22;
  const float a1 = fmaf(-M[1][3],a3,fmaf(-M[1][2],a2,M[1][4]))*i11;
  const float b1 = fmaf(-M[1][3],b3,fmaf(-M[1][2],b2,M[1][5]))*i11;
  const float a0 = fmaf(-M[0][3],a3,fmaf(-M[0][2],a2,fmaf(-M[0][1],a1,M[0][4])))*i00;
  const float b0 = fmaf(-M[0][3],b3,fmaf(-M[0][2],b2,fmaf(-M[0][1],b1,M[0][5])))*i00;
  s1 = make_float4(-a0,-a1,-a2,-a3);
  s2 = make_float4(-b0,-b1,-b2,-b3);
}

// MODE: 0 = f32 gains in d_ws, 1 = bf16 gains in d_ws, 2 = gains in LDS
template <int MODE>
__global__ __launch_bounds__(64, 2) void mpc_kernel(
    const void* __restrict__ x_init, const void* __restrict__ Qm,
    const void* __restrict__ pm, const void* __restrict__ Am,
    const void* __restrict__ Bm, void* __restrict__ outv,
    void* __restrict__ wsv)
{
  __shared__ float sF[192];     // col-major: sF[a*12+i] = F[i][a], F=[A|B] 12x16
  __shared__ float sFr[320];    // row-major, stride 20: sFr[i*20+a]
  __shared__ float sV[4*VES];   // per-elem V col-major 12x12
  __shared__ float sQt[4*QTE];  // per-elem Qt cols 12..15, col stride QS
  __shared__ float squ[4*20];   // per-elem qu (qt rows 12..15)
  __shared__ float svv[4*20];   // per-elem v (12)
  __shared__ float sx[4*20];    // per-elem x broadcast (fwd)
  __shared__ float sG[(MODE == 2) ? (4*2600) : 4];

  const int tid = threadIdx.x;
  const int c = tid & 15;
  const int g = tid >> 4;
  const int b = (int)blockIdx.x * 4 + g;

  // ---- runtime dtype detection (wave-uniform) ----
  bool isf32;
  {
    const unsigned int* aw = (const unsigned int*)Am;
    int insane = 0;
    #pragma unroll 4
    for (int k = 0; k < 72; ++k) {
      const unsigned int w = aw[k];
      const unsigned short h0 = (unsigned short)(w & 0xFFFFu);
      const unsigned short h1 = (unsigned short)(w >> 16);
      const int e0 = (h0 >> 7) & 0xFF, e1 = (h1 >> 7) & 0xFF;
      insane += (((h0 & 0x7FFF) != 0) && (e0 < 107 || e0 > 132)) ? 1 : 0;
      insane += (((h1 & 0x7FFF) != 0) && (e1 < 107 || e1 > 132)) ? 1 : 0;
    }
    isf32 = (insane > 8);
  }

  const float* const xf = (const float*)x_init;
  const float* const Qf = (const float*)Qm;
  const float* const pf = (const float*)pm;
  const float* const Af = (const float*)Am;
  const float* const Bf = (const float*)Bm;
  const unsigned short* const xh = (const unsigned short*)x_init;
  const unsigned short* const Qh = (const unsigned short*)Qm;
  const unsigned short* const ph = (const unsigned short*)pm;
  const unsigned short* const Ah = (const unsigned short*)Am;
  const unsigned short* const Bh = (const unsigned short*)Bm;

  // ---- stage F; zero V, v ----
  for (int idx = tid; idx < 320; idx += 64) {
    const int i_ = idx / 20, a_ = idx - i_ * 20;
    float fv = 0.f;
    if (i_ < 12 && a_ < 16) {
      if (a_ < 12) fv = isf32 ? Af[i_*12 + a_] : bf2f(Ah[i_*12 + a_]);
      else         fv = isf32 ? Bf[i_*4 + (a_-12)] : bf2f(Bh[i_*4 + (a_-12)]);
    }
    sFr[idx] = fv;
  }
  for (int idx = tid; idx < 192; idx += 64) {
    const int a_ = idx / 12, i_ = idx - a_ * 12;
    float fv;
    if (a_ < 12) fv = isf32 ? Af[i_*12 + a_] : bf2f(Ah[i_*12 + a_]);
    else         fv = isf32 ? Bf[i_*4 + (a_-12)] : bf2f(Bh[i_*4 + (a_-12)]);
    sF[idx] = fv;
  }
  for (int idx = tid; idx < 4*VES; idx += 64) sV[idx] = 0.f;
  for (int idx = tid; idx < 4*20; idx += 64) svv[idx] = 0.f;
  __syncthreads();

  float Fc[12];
  #pragma unroll
  for (int i = 0; i < 12; ++i) Fc[i] = sF[c*12 + i];
  const float Qd = isf32 ? Qf[b*16 + c] : bf2f(Qh[b*16 + c]);
  const float pc = isf32 ? pf[b*16 + c] : bf2f(ph[b*16 + c]);

  float* const vbase = &sV[g*VES];
  float* const qtb   = &sQt[g*QTE];
  float* const qub   = &squ[g*20];
  float* const vvb   = &svv[g*20];
  float* const sxg   = &sx[g*20];
  float* const gbl   = (MODE == 2) ? &sG[g*2600] : nullptr;

  float* const wsf = (float*)wsv;
  unsigned short* const wsh = (unsigned short*)wsv;

  // ----------------- backward Riccati pass -----------------
  for (int it = 0; it < TT; ++it) {
    // opaque SGPR zero: keeps per-step F-row loads uniform (scalar path) but
    // not loop-invariant (prevents LICM hoisting 192 floats -> SGPR spill)
    int zof = 0;
    __asm__ volatile("" : "+s"(zof));
    const float* const Afo = Af + zof;
    const float* const Bfo = Bf + zof;
    const unsigned short* const Aho = Ah + zof;
    const unsigned short* const Bho = Bh + zof;

    // W = V * F[:,c]
    float W[12];
    #pragma unroll
    for (int i = 0; i < 12; ++i) W[i] = 0.f;
    #pragma unroll
    for (int j = 0; j < 12; ++j) {
      const float fj = Fc[j];
      const float4 v0 = *(const float4*)(vbase + j*12);
      const float4 v1 = *(const float4*)(vbase + j*12 + 4);
      const float4 v2 = *(const float4*)(vbase + j*12 + 8);
      W[0]=fmaf(v0.x,fj,W[0]); W[1]=fmaf(v0.y,fj,W[1]); W[2]=fmaf(v0.z,fj,W[2]); W[3]=fmaf(v0.w,fj,W[3]);
      W[4]=fmaf(v1.x,fj,W[4]); W[5]=fmaf(v1.y,fj,W[5]); W[6]=fmaf(v1.z,fj,W[6]); W[7]=fmaf(v1.w,fj,W[7]);
      W[8]=fmaf(v2.x,fj,W[8]); W[9]=fmaf(v2.y,fj,W[9]); W[10]=fmaf(v2.z,fj,W[10]); W[11]=fmaf(v2.w,fj,W[11]);
    }
    // qt[c] = p[c] + F[:,c].v
    float qts = pc;
    {
      const float4 vv0 = *(const float4*)(vvb);
      const float4 vv1 = *(const float4*)(vvb + 4);
      const float4 vv2 = *(const float4*)(vvb + 8);
      qts = fmaf(Fc[0],vv0.x,qts); qts = fmaf(Fc[1],vv0.y,qts); qts = fmaf(Fc[2],vv0.z,qts); qts = fmaf(Fc[3],vv0.w,qts);
      qts = fmaf(Fc[4],vv1.x,qts); qts = fmaf(Fc[5],vv1.y,qts); qts = fmaf(Fc[6],vv1.z,qts); qts = fmaf(Fc[7],vv1.w,qts);
      qts = fmaf(Fc[8],vv2.x,qts); qts = fmaf(Fc[9],vv2.y,qts); qts = fmaf(Fc[10],vv2.z,qts); qts = fmaf(Fc[11],vv2.w,qts);
    }
    // Qt column c via row-loop: qtc[a] = sum_i F[i][a]*W[i]; F rows from
    // GLOBAL A/B with uniform addresses -> s_load (off the DS pipe)
    float qtc[16];
    #pragma unroll
    for (int a = 0; a < 16; ++a) qtc[a] = 0.f;
    #pragma unroll
    for (int i = 0; i < 12; ++i) {
      float fr[16];
      if (isf32) {
        const float4 ra0 = *(const float4*)(Afo + i*12);
        const float4 ra1 = *(const float4*)(Afo + i*12 + 4);
        const float4 ra2 = *(const float4*)(Afo + i*12 + 8);
        const float4 rb  = *(const float4*)(Bfo + i*4);
        fr[0]=ra0.x; fr[1]=ra0.y; fr[2]=ra0.z; fr[3]=ra0.w;
        fr[4]=ra1.x; fr[5]=ra1.y; fr[6]=ra1.z; fr[7]=ra1.w;
        fr[8]=ra2.x; fr[9]=ra2.y; fr[10]=ra2.z; fr[11]=ra2.w;
        fr[12]=rb.x; fr[13]=rb.y; fr[14]=rb.z; fr[15]=rb.w;
      } else {
        const ushort4 ha0 = *(const ushort4*)(Aho + i*12);
        const ushort4 ha1 = *(const ushort4*)(Aho + i*12 + 4);
        const ushort4 ha2 = *(const ushort4*)(Aho + i*12 + 8);
        const ushort4 hb  = *(const ushort4*)(Bho + i*4);
        fr[0]=bf2f(ha0.x); fr[1]=bf2f(ha0.y); fr[2]=bf2f(ha0.z); fr[3]=bf2f(ha0.w);
        fr[4]=bf2f(ha1.x); fr[5]=bf2f(ha1.y); fr[6]=bf2f(ha1.z); fr[7]=bf2f(ha1.w);
        fr[8]=bf2f(ha2.x); fr[9]=bf2f(ha2.y); fr[10]=bf2f(ha2.z); fr[11]=bf2f(ha2.w);
        fr[12]=bf2f(hb.x); fr[13]=bf2f(hb.y); fr[14]=bf2f(hb.z); fr[15]=bf2f(hb.w);
      }
      const float wi = W[i];
      #pragma unroll
      for (int a = 0; a < 16; ++a) qtc[a] = fmaf(fr[a], wi, qtc[a]);
    }
    // diagonal Q
    #pragma unroll
    for (int a = 0; a < 16; ++a) qtc[a] += (a == c) ? Qd : 0.f;

    // only cols 12..15 round-trip LDS
    if (c >= 12) {
      float* qa = qtb + (c-12)*QS;
      *(float4*)(qa     ) = make_float4(qtc[0],qtc[1],qtc[2],qtc[3]);
      *(float4*)(qa +  4) = make_float4(qtc[4],qtc[5],qtc[6],qtc[7]);
      *(float4*)(qa +  8) = make_float4(qtc[8],qtc[9],qtc[10],qtc[11]);
      *(float4*)(qa + 12) = make_float4(qtc[12],qtc[13],qtc[14],qtc[15]);
      qub[c-12] = qts;
    }
    __builtin_amdgcn_wave_barrier();   // single-wave block: DS in-order

    const float4 q0 = *(const float4*)(qtb + 0*QS + 12);
    const float4 q1 = *(const float4*)(qtb + 1*QS + 12);
    const float4 q2 = *(const float4*)(qtb + 2*QS + 12);
    const float4 q3 = *(const float4*)(qtb + 3*QS + 12);
    const float4 quv = *(const float4*)(qub);

    float4 Kc, kf;
    lu46(q0,q1,q2,q3, make_float4(qtc[12],qtc[13],qtc[14],qtc[15]), quv, Kc, kf);

    // store gains: [t][b][col 0..12][4], col 12 = kff; t = TT-1-it
    if (c < 13) {
      float4 gw;
      gw.x = (c < 12) ? Kc.x : kf.x;
      gw.y = (c < 12) ? Kc.y : kf.y;
      gw.z = (c < 12) ? Kc.z : kf.z;
      gw.w = (c < 12) ? Kc.w : kf.w;
      if (MODE == 2) {
        *(float4*)(gbl + (TT-1-it)*52 + c*4) = gw;
      } else {
        const size_t off = ((size_t)(TT-1-it)*NBB + b)*52 + (size_t)c*4;
        if (MODE == 1) {
          ushort4 us;
          us.x = f2bf(gw.x); us.y = f2bf(gw.y); us.z = f2bf(gw.z); us.w = f2bf(gw.w);
          *(ushort4*)(wsh + off) = us;
        } else {
          *(float4*)(wsf + off) = gw;
        }
      }
    }

    // Vn[:,c] = Qxx[:,c] + Qxu*K[:,c]; vn[c] = qt[c] + Qxu[c,:].kff
    if (c < 12) {
      float Vn[12];
      #pragma unroll
      for (int i = 0; i < 12; ++i) Vn[i] = qtc[i];
      #pragma unroll
      for (int u = 0; u < 4; ++u) {
        const float ku = (u==0)?Kc.x:((u==1)?Kc.y:((u==2)?Kc.z:Kc.w));
        const float4 a0 = *(const float4*)(qtb + u*QS);
        const float4 a1 = *(const float4*)(qtb + u*QS + 4);
        const float4 a2 = *(const float4*)(qtb + u*QS + 8);
        Vn[0]=fmaf(a0.x,ku,Vn[0]); Vn[1]=fmaf(a0.y,ku,Vn[1]); Vn[2]=fmaf(a0.z,ku,Vn[2]); Vn[3]=fmaf(a0.w,ku,Vn[3]);
        Vn[4]=fmaf(a1.x,ku,Vn[4]); Vn[5]=fmaf(a1.y,ku,Vn[5]); Vn[6]=fmaf(a1.z,ku,Vn[6]); Vn[7]=fmaf(a1.w,ku,Vn[7]);
        Vn[8]=fmaf(a2.x,ku,Vn[8]); Vn[9]=fmaf(a2.y,ku,Vn[9]); Vn[10]=fmaf(a2.z,ku,Vn[10]); Vn[11]=fmaf(a2.w,ku,Vn[11]);
      }
      float vnc = qts;
      vnc = fmaf(qtc[12],kf.x,vnc); vnc = fmaf(qtc[13],kf.y,vnc);
      vnc = fmaf(qtc[14],kf.z,vnc); vnc = fmaf(qtc[15],kf.w,vnc);
      *(float4*)(vbase + c*12    ) = make_float4(Vn[0],Vn[1],Vn[2],Vn[3]);
      *(float4*)(vbase + c*12 + 4) = make_float4(Vn[4],Vn[5],Vn[6],Vn[7]);
      *(float4*)(vbase + c*12 + 8) = make_float4(Vn[8],Vn[9],Vn[10],Vn[11]);
      vvb[c] = vnc;
    }
    __builtin_amdgcn_wave_barrier();
  }

  // ----------------- forward rollout -----------------
  if (MODE != 2) __threadfence();  // drain own gain stores before reading back

  float xc = 0.f;
  if (c < 12) xc = isf32 ? xf[b*12 + c] : bf2f(xh[b*12 + c]);

  float* const outf = (float*)outv;
  unsigned short* const outh = (unsigned short*)outv;

  auto loadg = [&](int t) -> float4 {
    if (c >= 13) return make_float4(0.f,0.f,0.f,0.f);
    if (MODE == 2) return *(const float4*)(gbl + t*52 + c*4);
    const size_t off = ((size_t)t*NBB + b)*52 + (size_t)c*4;
    if (MODE == 1) {
      const ushort4 us = *(const ushort4*)(wsh + off);
      return make_float4(bf2f(us.x),bf2f(us.y),bf2f(us.z),bf2f(us.w));
    }
    return *(const float4*)(wsf + off);
  };

  float4 gv = loadg(0);

  for (int t = 0; t < TT; ++t) {
    // broadcast x via LDS (intra-wave, in-order DS)
    if (c < 12) sxg[c] = xc;
    __builtin_amdgcn_wave_barrier();
    const float4 x0 = *(const float4*)(sxg);
    const float4 x1 = *(const float4*)(sxg + 4);
    const float4 x2 = *(const float4*)(sxg + 8);

    // u = sum_c K[:,c]*x[c] + kff via DPP row_ror reduction
    const float s = (c < 12) ? xc : 1.0f;
    const float u0 = rrsum16(gv.x*s), u1 = rrsum16(gv.y*s), u2 = rrsum16(gv.z*s), u3 = rrsum16(gv.w*s);

    if (c == 0) {
      const size_t o4 = ((size_t)t*NBB + b)*4;
      if (isf32) {
        *(float4*)(outf + o4) = make_float4(u0,u1,u2,u3);
      } else {
        ushort4 us;
        us.x = f2bf(u0); us.y = f2bf(u1); us.z = f2bf(u2); us.w = f2bf(u3);
        *(ushort4*)(outh + o4) = us;
      }
    }

    // prefetch next gains while x-update computes
    float4 gn = make_float4(0,0,0,0);
    if (t + 1 < TT) gn = loadg(t+1);

    // x'[c] = F[c,:] . [x;u]
    const float4 fr0 = *(const float4*)(sFr + c*20);
    const float4 fr1 = *(const float4*)(sFr + c*20 + 4);
    const float4 fr2 = *(const float4*)(sFr + c*20 + 8);
    const float4 frB = *(const float4*)(sFr + c*20 + 12);
    float xp = fr0.x*x0.x;
    xp = fmaf(fr0.y,x0.y,xp); xp = fmaf(fr0.z,x0.z,xp); xp = fmaf(fr0.w,x0.w,xp);
    xp = fmaf(fr1.x,x1.x,xp); xp = fmaf(fr1.y,x1.y,xp); xp = fmaf(fr1.z,x1.z,xp); xp = fmaf(fr1.w,x1.w,xp);
    xp = fmaf(fr2.x,x2.x,xp); xp = fmaf(fr2.y,x2.y,xp); xp = fmaf(fr2.z,x2.z,xp); xp = fmaf(fr2.w,x2.w,xp);
    xp = fmaf(frB.x,u0,xp); xp = fmaf(frB.y,u1,xp); xp = fmaf(frB.z,u2,xp); xp = fmaf(frB.w,u3,xp);
    xc = xp;
    gv = gn;
  }
}

extern "C" void kernel_launch(void* const* d_in, const int* in_sizes, int n_in,
                              void* d_out, int out_size, void* d_ws, size_t ws_size,
                              hipStream_t stream) {
  (void)in_sizes; (void)n_in; (void)out_size;
  const size_t needF = (size_t)TT * NBB * 52 * sizeof(float);          // 85.2 MB
  const size_t needH = (size_t)TT * NBB * 52 * sizeof(unsigned short); // 42.6 MB
  dim3 grid(NBB / 4), block(64);
  if (d_ws != nullptr && ws_size >= needF) {
    mpc_kernel<0><<<grid, block, 0, stream>>>(d_in[0], d_in[1], d_in[2], d_in[3], d_in[4], d_out, d_ws);
  } else if (d_ws != nullptr && ws_size >= needH) {
    mpc_kernel<1><<<grid, block, 0, stream>>>(d_in[0], d_in[1], d_in[2], d_in[3], d_in[4], d_out, d_ws);
  } else {
    mpc_kernel<2><<<grid, block, 0, stream>>>(d_in[0], d_in[1], d_in[2], d_in[3], d_in[4], d_out, d_ws);
  }
}

// Round 7
// 236.918 us; speedup vs baseline: 1.3042x; 1.2535x over previous
//
#include <hip/hip_runtime.h>
#include <hip/hip_bf16.h>

// LQR-MPC: T=50, N=12, M=4, NSC=16, NB=8192.
// 4 elems per 64-lane wave; lane (c=tid&15, g=tid>>4), element b=blk*4+g.
// U-SCHEME: V never round-trips LDS. Lane c holds Vn[:,c] (= V row c by
// symmetry) in REGISTERS and computes U[c][:] = V[c,:]*F locally (scalar F).
// Qt[:,c] = F^T U[:,c] needs only a U-transpose via LDS (4 b128 w + 12 b32 r).
// Quu/Qxu exchange as before. DS/wave-step 65 -> ~42. Backward pass is
// templated on dtype so f32/bf16 paths can't be if-converted together.
// Single-wave blocks: DS in-order -> wave_barrier() fences only.
// Vn = Qxx + Qxu*K exactly (K^T Qux + K^T Quu K cancels).
#define TT 50
#define NBB 8192
#define QS  20    // Qt col stride (floats)
#define QTE 88    // Qt per-elem stride
#define US  20    // U row stride (floats)
#define UES 248   // U per-elem stride (248%32=24 -> staggered banks)

__device__ __forceinline__ unsigned short f2bf(float f) {
  unsigned int u = __float_as_uint(f);
  u = (u + 0x7FFFu + ((u >> 16) & 1u)) >> 16;   // RNE
  return (unsigned short)u;
}
__device__ __forceinline__ float bf2f(unsigned short h) {
  return __uint_as_float(((unsigned int)h) << 16);
}
__device__ __forceinline__ float rrsum16(float v) {
  int t;
  t = __builtin_amdgcn_update_dpp(0, __float_as_int(v), 0x128, 0xF, 0xF, true); v += __int_as_float(t);
  t = __builtin_amdgcn_update_dpp(0, __float_as_int(v), 0x124, 0xF, 0xF, true); v += __int_as_float(t);
  t = __builtin_amdgcn_update_dpp(0, __float_as_int(v), 0x122, 0xF, 0xF, true); v += __int_as_float(t);
  t = __builtin_amdgcn_update_dpp(0, __float_as_int(v), 0x121, 0xF, 0xF, true); v += __int_as_float(t);
  return v;
}

__device__ __forceinline__ void lu46(const float4 q0, const float4 q1, const float4 q2, const float4 q3,
                                     const float4 r1, const float4 r2, float4& s1, float4& s2) {
  float M[4][6];
  M[0][0]=q0.x; M[1][0]=q0.y; M[2][0]=q0.z; M[3][0]=q0.w;
  M[0][1]=q1.x; M[1][1]=q1.y; M[2][1]=q1.z; M[3][1]=q1.w;
  M[0][2]=q2.x; M[1][2]=q2.y; M[2][2]=q2.z; M[3][2]=q2.w;
  M[0][3]=q3.x; M[1][3]=q3.y; M[2][3]=q3.z; M[3][3]=q3.w;
  M[0][4]=r1.x; M[1][4]=r1.y; M[2][4]=r1.z; M[3][4]=r1.w;
  M[0][5]=r2.x; M[1][5]=r2.y; M[2][5]=r2.z; M[3][5]=r2.w;
  #pragma unroll
  for (int k = 0; k < 4; ++k) {
    #pragma unroll
    for (int i = k+1; i < 4; ++i) {
      const bool sw = fabsf(M[i][k]) > fabsf(M[k][k]);
      #pragma unroll
      for (int j = 0; j < 6; ++j) {
        const float a_ = M[k][j], b_ = M[i][j];
        M[k][j] = sw ? b_ : a_;
        M[i][j] = sw ? a_ : b_;
      }
    }
    const float inv = __builtin_amdgcn_rcpf(M[k][k]);
    #pragma unroll
    for (int i = k+1; i < 4; ++i) {
      const float f = M[i][k] * inv;
      #pragma unroll
      for (int j = k+1; j < 6; ++j) M[i][j] = fmaf(-f, M[k][j], M[i][j]);
    }
  }
  const float i33 = __builtin_amdgcn_rcpf(M[3][3]);
  const float i22 = __builtin_amdgcn_rcpf(M[2][2]);
  const float i11 = __builtin_amdgcn_rcpf(M[1][1]);
  const float i00 = __builtin_amdgcn_rcpf(M[0][0]);
  const float a3 = M[3][4]*i33;
  const float b3 = M[3][5]*i33;
  const float a2 = fmaf(-M[2][3],a3,M[2][4])*i22;
  const float b2 = fmaf(-M[2][3],b3,M[2][5])*i22;
  const float a1 = fmaf(-M[1][3],a3,fmaf(-M[1][2],a2,M[1][4]))*i11;
  const float b1 = fmaf(-M[1][3],b3,fmaf(-M[1][2],b2,M[1][5]))*i11;
  const float a0 = fmaf(-M[0][3],a3,fmaf(-M[0][2],a2,fmaf(-M[0][1],a1,M[0][4])))*i00;
  const float b0 = fmaf(-M[0][3],b3,fmaf(-M[0][2],b2,fmaf(-M[0][1],b1,M[0][5])))*i00;
  s1 = make_float4(-a0,-a1,-a2,-a3);
  s2 = make_float4(-b0,-b1,-b2,-b3);
}

// Load F row i (16 floats) from global A/B with wave-uniform addresses.
template <bool F32>
__device__ __forceinline__ void load_frow(const float* Af, const float* Bf,
                                          const unsigned short* Ah, const unsigned short* Bh,
                                          int i, float* fr) {
  if (F32) {
    const float4 r0 = *(const float4*)(Af + i*12);
    const float4 r1 = *(const float4*)(Af + i*12 + 4);
    const float4 r2 = *(const float4*)(Af + i*12 + 8);
    const float4 rb = *(const float4*)(Bf + i*4);
    fr[0]=r0.x; fr[1]=r0.y; fr[2]=r0.z; fr[3]=r0.w;
    fr[4]=r1.x; fr[5]=r1.y; fr[6]=r1.z; fr[7]=r1.w;
    fr[8]=r2.x; fr[9]=r2.y; fr[10]=r2.z; fr[11]=r2.w;
    fr[12]=rb.x; fr[13]=rb.y; fr[14]=rb.z; fr[15]=rb.w;
  } else {
    const ushort4 h0 = *(const ushort4*)(Ah + i*12);
    const ushort4 h1 = *(const ushort4*)(Ah + i*12 + 4);
    const ushort4 h2 = *(const ushort4*)(Ah + i*12 + 8);
    const ushort4 hb = *(const ushort4*)(Bh + i*4);
    fr[0]=bf2f(h0.x); fr[1]=bf2f(h0.y); fr[2]=bf2f(h0.z); fr[3]=bf2f(h0.w);
    fr[4]=bf2f(h1.x); fr[5]=bf2f(h1.y); fr[6]=bf2f(h1.z); fr[7]=bf2f(h1.w);
    fr[8]=bf2f(h2.x); fr[9]=bf2f(h2.y); fr[10]=bf2f(h2.z); fr[11]=bf2f(h2.w);
    fr[12]=bf2f(hb.x); fr[13]=bf2f(hb.y); fr[14]=bf2f(hb.z); fr[15]=bf2f(hb.w);
  }
}

template <int MODE, bool F32>
__device__ __forceinline__ void backward_pass(
    const int c, const int g, const int b,
    const float* __restrict__ Af, const float* __restrict__ Bf,
    const unsigned short* __restrict__ Ah, const unsigned short* __restrict__ Bh,
    const float Qd, const float pc, const float* __restrict__ Fc,
    float* __restrict__ sUb, float* __restrict__ qtb, float* __restrict__ qub,
    float* __restrict__ vvb, float* __restrict__ gbl,
    float* __restrict__ wsf, unsigned short* __restrict__ wsh)
{
  float Vn[12];
  #pragma unroll
  for (int i = 0; i < 12; ++i) Vn[i] = 0.f;
  float vn = 0.f;

  for (int it = 0; it < TT; ++it) {
    // opaque SGPR zero: per-step uniform F loads, LICM blocked
    int zof = 0;
    __asm__ volatile("" : "+s"(zof));
    const float* Afo = Af + zof;
    const float* Bfo = Bf + zof;
    const unsigned short* Aho = Ah + zof;
    const unsigned short* Bho = Bh + zof;

    // publish v (from previous step) and compute qts = p[c] + F[:,c].v
    if (c < 12) vvb[c] = vn;
    __builtin_amdgcn_wave_barrier();
    float qts = pc;
    {
      const float4 v0 = *(const float4*)(vvb);
      const float4 v1 = *(const float4*)(vvb + 4);
      const float4 v2 = *(const float4*)(vvb + 8);
      qts = fmaf(Fc[0],v0.x,qts); qts = fmaf(Fc[1],v0.y,qts); qts = fmaf(Fc[2],v0.z,qts); qts = fmaf(Fc[3],v0.w,qts);
      qts = fmaf(Fc[4],v1.x,qts); qts = fmaf(Fc[5],v1.y,qts); qts = fmaf(Fc[6],v1.z,qts); qts = fmaf(Fc[7],v1.w,qts);
      qts = fmaf(Fc[8],v2.x,qts); qts = fmaf(Fc[9],v2.y,qts); qts = fmaf(Fc[10],v2.z,qts); qts = fmaf(Fc[11],v2.w,qts);
    }

    // U row c: U[a] = sum_j V[c][j]*F[j][a] = sum_j Vn[j]*F[j][a] — REGISTERS ONLY
    float U[16];
    #pragma unroll
    for (int a = 0; a < 16; ++a) U[a] = 0.f;
    #pragma unroll
    for (int j = 0; j < 12; ++j) {
      float fr[16];
      load_frow<F32>(Afo, Bfo, Aho, Bho, j, fr);
      const float vj = Vn[j];
      #pragma unroll
      for (int a = 0; a < 16; ++a) U[a] = fmaf(fr[a], vj, U[a]);
    }
    if (c < 12) {
      *(float4*)(sUb + c*US     ) = make_float4(U[0],U[1],U[2],U[3]);
      *(float4*)(sUb + c*US +  4) = make_float4(U[4],U[5],U[6],U[7]);
      *(float4*)(sUb + c*US +  8) = make_float4(U[8],U[9],U[10],U[11]);
      *(float4*)(sUb + c*US + 12) = make_float4(U[12],U[13],U[14],U[15]);
    }
    __builtin_amdgcn_wave_barrier();

    // read U column c (12 strided b32, per-lane addresses)
    float Uc[12];
    #pragma unroll
    for (int i = 0; i < 12; ++i) Uc[i] = sUb[i*US + c];

    // qtc[a] = sum_i F[i][a]*U[i][c] (+ diag Q)
    float qtc[16];
    #pragma unroll
    for (int a = 0; a < 16; ++a) qtc[a] = 0.f;
    #pragma unroll
    for (int i = 0; i < 12; ++i) {
      float fr[16];
      load_frow<F32>(Afo, Bfo, Aho, Bho, i, fr);
      const float ui = Uc[i];
      #pragma unroll
      for (int a = 0; a < 16; ++a) qtc[a] = fmaf(fr[a], ui, qtc[a]);
    }
    #pragma unroll
    for (int a = 0; a < 16; ++a) qtc[a] += (a == c) ? Qd : 0.f;

    // publish cols 12..15 (Quu rows + Qxu cols) and qu
    if (c >= 12) {
      float* qa = qtb + (c-12)*QS;
      *(float4*)(qa     ) = make_float4(qtc[0],qtc[1],qtc[2],qtc[3]);
      *(float4*)(qa +  4) = make_float4(qtc[4],qtc[5],qtc[6],qtc[7]);
      *(float4*)(qa +  8) = make_float4(qtc[8],qtc[9],qtc[10],qtc[11]);
      *(float4*)(qa + 12) = make_float4(qtc[12],qtc[13],qtc[14],qtc[15]);
      qub[c-12] = qts;
    }
    __builtin_amdgcn_wave_barrier();

    const float4 q0 = *(const float4*)(qtb + 0*QS + 12);
    const float4 q1 = *(const float4*)(qtb + 1*QS + 12);
    const float4 q2 = *(const float4*)(qtb + 2*QS + 12);
    const float4 q3 = *(const float4*)(qtb + 3*QS + 12);
    const float4 quv = *(const float4*)(qub);

    float4 Kc, kf;
    lu46(q0,q1,q2,q3, make_float4(qtc[12],qtc[13],qtc[14],qtc[15]), quv, Kc, kf);

    // store gains: [t][b][col 0..12][4], col 12 = kff; t = TT-1-it
    if (c < 13) {
      float4 gw;
      gw.x = (c < 12) ? Kc.x : kf.x;
      gw.y = (c < 12) ? Kc.y : kf.y;
      gw.z = (c < 12) ? Kc.z : kf.z;
      gw.w = (c < 12) ? Kc.w : kf.w;
      if (MODE == 2) {
        *(float4*)(gbl + (TT-1-it)*52 + c*4) = gw;
      } else {
        const size_t off = ((size_t)(TT-1-it)*NBB + b)*52 + (size_t)c*4;
        if (MODE == 1) {
          ushort4 us;
          us.x = f2bf(gw.x); us.y = f2bf(gw.y); us.z = f2bf(gw.z); us.w = f2bf(gw.w);
          *(ushort4*)(wsh + off) = us;
        } else {
          *(float4*)(wsf + off) = gw;
        }
      }
    }

    // Vn[:,c] = Qxx[:,c] + Qxu*K[:,c]  (registers; no V store)
    #pragma unroll
    for (int i = 0; i < 12; ++i) Vn[i] = qtc[i];
    #pragma unroll
    for (int u = 0; u < 4; ++u) {
      const float ku = (u==0)?Kc.x:((u==1)?Kc.y:((u==2)?Kc.z:Kc.w));
      const float4 a0 = *(const float4*)(qtb + u*QS);
      const float4 a1 = *(const float4*)(qtb + u*QS + 4);
      const float4 a2 = *(const float4*)(qtb + u*QS + 8);
      Vn[0]=fmaf(a0.x,ku,Vn[0]); Vn[1]=fmaf(a0.y,ku,Vn[1]); Vn[2]=fmaf(a0.z,ku,Vn[2]); Vn[3]=fmaf(a0.w,ku,Vn[3]);
      Vn[4]=fmaf(a1.x,ku,Vn[4]); Vn[5]=fmaf(a1.y,ku,Vn[5]); Vn[6]=fmaf(a1.z,ku,Vn[6]); Vn[7]=fmaf(a1.w,ku,Vn[7]);
      Vn[8]=fmaf(a2.x,ku,Vn[8]); Vn[9]=fmaf(a2.y,ku,Vn[9]); Vn[10]=fmaf(a2.z,ku,Vn[10]); Vn[11]=fmaf(a2.w,ku,Vn[11]);
    }
    // vn = qts + Qxu[c,:].kff  (Qxu[c,u] = qtc[12+u] by symmetry)
    vn = qts;
    vn = fmaf(qtc[12],kf.x,vn); vn = fmaf(qtc[13],kf.y,vn);
    vn = fmaf(qtc[14],kf.z,vn); vn = fmaf(qtc[15],kf.w,vn);
    __builtin_amdgcn_wave_barrier();
  }
}

// MODE: 0 = f32 gains in d_ws, 1 = bf16 gains in d_ws, 2 = gains in LDS
template <int MODE>
__global__ __launch_bounds__(64, 2) void mpc_kernel(
    const void* __restrict__ x_init, const void* __restrict__ Qm,
    const void* __restrict__ pm, const void* __restrict__ Am,
    const void* __restrict__ Bm, void* __restrict__ outv,
    void* __restrict__ wsv)
{
  __shared__ float sF[192];     // col-major (init Fc only)
  __shared__ float sFr[320];    // row-major stride 20 (forward pass)
  __shared__ float sU[4*UES];   // per-elem U, rows stride US
  __shared__ float sQt[4*QTE];  // per-elem Qt cols 12..15
  __shared__ float squ[4*20];
  __shared__ float svv[4*20];
  __shared__ float sx[4*20];
  __shared__ float sG[(MODE == 2) ? (4*2600) : 4];

  const int tid = threadIdx.x;
  const int c = tid & 15;
  const int g = tid >> 4;
  const int b = (int)blockIdx.x * 4 + g;

  // ---- runtime dtype detection (wave-uniform) ----
  bool isf32;
  {
    const unsigned int* aw = (const unsigned int*)Am;
    int insane = 0;
    #pragma unroll 4
    for (int k = 0; k < 72; ++k) {
      const unsigned int w = aw[k];
      const unsigned short h0 = (unsigned short)(w & 0xFFFFu);
      const unsigned short h1 = (unsigned short)(w >> 16);
      const int e0 = (h0 >> 7) & 0xFF, e1 = (h1 >> 7) & 0xFF;
      insane += (((h0 & 0x7FFF) != 0) && (e0 < 107 || e0 > 132)) ? 1 : 0;
      insane += (((h1 & 0x7FFF) != 0) && (e1 < 107 || e1 > 132)) ? 1 : 0;
    }
    isf32 = (insane > 8);
  }

  const float* const xf = (const float*)x_init;
  const float* const Qf = (const float*)Qm;
  const float* const pf = (const float*)pm;
  const float* const Af = (const float*)Am;
  const float* const Bf = (const float*)Bm;
  const unsigned short* const xh = (const unsigned short*)x_init;
  const unsigned short* const Qh = (const unsigned short*)Qm;
  const unsigned short* const ph = (const unsigned short*)pm;
  const unsigned short* const Ah = (const unsigned short*)Am;
  const unsigned short* const Bh = (const unsigned short*)Bm;

  // ---- stage F (Fc + forward rows); zero v ----
  for (int idx = tid; idx < 320; idx += 64) {
    const int i_ = idx / 20, a_ = idx - i_ * 20;
    float fv = 0.f;
    if (i_ < 12 && a_ < 16) {
      if (a_ < 12) fv = isf32 ? Af[i_*12 + a_] : bf2f(Ah[i_*12 + a_]);
      else         fv = isf32 ? Bf[i_*4 + (a_-12)] : bf2f(Bh[i_*4 + (a_-12)]);
    }
    sFr[idx] = fv;
  }
  for (int idx = tid; idx < 192; idx += 64) {
    const int a_ = idx / 12, i_ = idx - a_ * 12;
    float fv;
    if (a_ < 12) fv = isf32 ? Af[i_*12 + a_] : bf2f(Ah[i_*12 + a_]);
    else         fv = isf32 ? Bf[i_*4 + (a_-12)] : bf2f(Bh[i_*4 + (a_-12)]);
    sF[idx] = fv;
  }
  for (int idx = tid; idx < 4*20; idx += 64) svv[idx] = 0.f;
  __syncthreads();

  float Fc[12];
  #pragma unroll
  for (int i = 0; i < 12; ++i) Fc[i] = sF[c*12 + i];
  const float Qd = isf32 ? Qf[b*16 + c] : bf2f(Qh[b*16 + c]);
  const float pc = isf32 ? pf[b*16 + c] : bf2f(ph[b*16 + c]);

  float* const sUb = &sU[g*UES];
  float* const qtb = &sQt[g*QTE];
  float* const qub = &squ[g*20];
  float* const vvb = &svv[g*20];
  float* const sxg = &sx[g*20];
  float* const gbl = (MODE == 2) ? &sG[g*2600] : nullptr;

  float* const wsf = (float*)wsv;
  unsigned short* const wsh = (unsigned short*)wsv;

  // ----------------- backward Riccati pass (single dtype path) -----------------
  if (isf32) {
    backward_pass<MODE, true >(c, g, b, Af, Bf, Ah, Bh, Qd, pc, Fc, sUb, qtb, qub, vvb, gbl, wsf, wsh);
  } else {
    backward_pass<MODE, false>(c, g, b, Af, Bf, Ah, Bh, Qd, pc, Fc, sUb, qtb, qub, vvb, gbl, wsf, wsh);
  }

  // ----------------- forward rollout -----------------
  if (MODE != 2) __threadfence();  // drain own gain stores before reading back

  float xc = 0.f;
  if (c < 12) xc = isf32 ? xf[b*12 + c] : bf2f(xh[b*12 + c]);

  float* const outf = (float*)outv;
  unsigned short* const outh = (unsigned short*)outv;

  auto loadg = [&](int t) -> float4 {
    if (c >= 13) return make_float4(0.f,0.f,0.f,0.f);
    if (MODE == 2) return *(const float4*)(gbl + t*52 + c*4);
    const size_t off = ((size_t)t*NBB + b)*52 + (size_t)c*4;
    if (MODE == 1) {
      const ushort4 us = *(const ushort4*)(wsh + off);
      return make_float4(bf2f(us.x),bf2f(us.y),bf2f(us.z),bf2f(us.w));
    }
    return *(const float4*)(wsf + off);
  };

  float4 gv = loadg(0);

  for (int t = 0; t < TT; ++t) {
    if (c < 12) sxg[c] = xc;
    __builtin_amdgcn_wave_barrier();
    const float4 x0 = *(const float4*)(sxg);
    const float4 x1 = *(const float4*)(sxg + 4);
    const float4 x2 = *(const float4*)(sxg + 8);

    const float s = (c < 12) ? xc : 1.0f;
    const float u0 = rrsum16(gv.x*s), u1 = rrsum16(gv.y*s), u2 = rrsum16(gv.z*s), u3 = rrsum16(gv.w*s);

    if (c == 0) {
      const size_t o4 = ((size_t)t*NBB + b)*4;
      if (isf32) {
        *(float4*)(outf + o4) = make_float4(u0,u1,u2,u3);
      } else {
        ushort4 us;
        us.x = f2bf(u0); us.y = f2bf(u1); us.z = f2bf(u2); us.w = f2bf(u3);
        *(ushort4*)(outh + o4) = us;
      }
    }

    float4 gn = make_float4(0,0,0,0);
    if (t + 1 < TT) gn = loadg(t+1);

    const float4 fr0 = *(const float4*)(sFr + c*20);
    const float4 fr1 = *(const float4*)(sFr + c*20 + 4);
    const float4 fr2 = *(const float4*)(sFr + c*20 + 8);
    const float4 frB = *(const float4*)(sFr + c*20 + 12);
    float xp = fr0.x*x0.x;
    xp = fmaf(fr0.y,x0.y,xp); xp = fmaf(fr0.z,x0.z,xp); xp = fmaf(fr0.w,x0.w,xp);
    xp = fmaf(fr1.x,x1.x,xp); xp = fmaf(fr1.y,x1.y,xp); xp = fmaf(fr1.z,x1.z,xp); xp = fmaf(fr1.w,x1.w,xp);
    xp = fmaf(fr2.x,x2.x,xp); xp = fmaf(fr2.y,x2.y,xp); xp = fmaf(fr2.z,x2.z,xp); xp = fmaf(fr2.w,x2.w,xp);
    xp = fmaf(frB.x,u0,xp); xp = fmaf(frB.y,u1,xp); xp = fmaf(frB.z,u2,xp); xp = fmaf(frB.w,u3,xp);
    xc = xp;
    gv = gn;
  }
}

extern "C" void kernel_launch(void* const* d_in, const int* in_sizes, int n_in,
                              void* d_out, int out_size, void* d_ws, size_t ws_size,
                              hipStream_t stream) {
  (void)in_sizes; (void)n_in; (void)out_size;
  const size_t needF = (size_t)TT * NBB * 52 * sizeof(float);          // 85.2 MB
  const size_t needH = (size_t)TT * NBB * 52 * sizeof(unsigned short); // 42.6 MB
  dim3 grid(NBB / 4), block(64);
  if (d_ws != nullptr && ws_size >= needF) {
    mpc_kernel<0><<<grid, block, 0, stream>>>(d_in[0], d_in[1], d_in[2], d_in[3], d_in[4], d_out, d_ws);
  } else if (d_ws != nullptr && ws_size >= needH) {
    mpc_kernel<1><<<grid, block, 0, stream>>>(d_in[0], d_in[1], d_in[2], d_in[3], d_in[4], d_out, d_ws);
  } else {
    mpc_kernel<2><<<grid, block, 0, stream>>>(d_in[0], d_in[1], d_in[2], d_in[3], d_in[4], d_out, d_ws);
  }
}

// Round 10
// 233.155 us; speedup vs baseline: 1.3252x; 1.0161x over previous
//
#include <hip/hip_runtime.h>
#include <hip/hip_bf16.h>

// LQR-MPC: T=50, N=12, M=4, NSC=16, NB=8192.
// == R7 (validated 191us, LU solve) + ONE change: the three FMA loops
// (U = V-row x F, qtc = F^T U-col, Vn update) run on packed float2
// (__builtin_elementwise_fma on ext_vector(2)) -> v_pk_fma_f32 on CDNA,
// halving the dominant VALU instruction count. Same ops, same order ->
// bit-identical arithmetic. CHOLESKY IS BANNED: NaN'd in R1/R8/R9; LU
// passed in R3-R7. Solve = branchless partial-pivot LU (lu46, rcpf).
// U-SCHEME: lane c holds Vn[:,c] (= V row c by symmetry) in registers;
// U row c = V[c,:]*F from s_load F rows (scalar path). One 16x16 U
// transpose via LDS per step. Single-wave blocks: DS in-order ->
// wave_barrier(). Vn = Qxx + Qxu*K exactly (K^T Qux + K^T Quu K cancels).
#define TT 50
#define NBB 8192
#define QS  20    // Qt col stride (floats)
#define QTE 88    // Qt per-elem stride
#define US  20    // U row stride (floats)
#define UES 248   // U per-elem stride (248%32=24 -> staggered banks)

typedef float f32x2 __attribute__((ext_vector_type(2)));

__device__ __forceinline__ unsigned short f2bf(float f) {
  unsigned int u = __float_as_uint(f);
  u = (u + 0x7FFFu + ((u >> 16) & 1u)) >> 16;   // RNE
  return (unsigned short)u;
}
__device__ __forceinline__ float bf2f(unsigned short h) {
  return __uint_as_float(((unsigned int)h) << 16);
}
__device__ __forceinline__ float rrsum16(float v) {
  int t;
  t = __builtin_amdgcn_update_dpp(0, __float_as_int(v), 0x128, 0xF, 0xF, true); v += __int_as_float(t);
  t = __builtin_amdgcn_update_dpp(0, __float_as_int(v), 0x124, 0xF, 0xF, true); v += __int_as_float(t);
  t = __builtin_amdgcn_update_dpp(0, __float_as_int(v), 0x122, 0xF, 0xF, true); v += __int_as_float(t);
  t = __builtin_amdgcn_update_dpp(0, __float_as_int(v), 0x121, 0xF, 0xF, true); v += __int_as_float(t);
  return v;
}

// Branchless partial-pivot LU on [Quu | r1 | r2]; s1 = -Quu^-1 r1, s2 = -Quu^-1 r2
__device__ __forceinline__ void lu46(const float4 q0, const float4 q1, const float4 q2, const float4 q3,
                                     const float4 r1, const float4 r2, float4& s1, float4& s2) {
  float M[4][6];
  M[0][0]=q0.x; M[1][0]=q0.y; M[2][0]=q0.z; M[3][0]=q0.w;
  M[0][1]=q1.x; M[1][1]=q1.y; M[2][1]=q1.z; M[3][1]=q1.w;
  M[0][2]=q2.x; M[1][2]=q2.y; M[2][2]=q2.z; M[3][2]=q2.w;
  M[0][3]=q3.x; M[1][3]=q3.y; M[2][3]=q3.z; M[3][3]=q3.w;
  M[0][4]=r1.x; M[1][4]=r1.y; M[2][4]=r1.z; M[3][4]=r1.w;
  M[0][5]=r2.x; M[1][5]=r2.y; M[2][5]=r2.z; M[3][5]=r2.w;
  #pragma unroll
  for (int k = 0; k < 4; ++k) {
    #pragma unroll
    for (int i = k+1; i < 4; ++i) {
      const bool sw = fabsf(M[i][k]) > fabsf(M[k][k]);
      #pragma unroll
      for (int j = 0; j < 6; ++j) {
        const float a_ = M[k][j], b_ = M[i][j];
        M[k][j] = sw ? b_ : a_;
        M[i][j] = sw ? a_ : b_;
      }
    }
    const float inv = __builtin_amdgcn_rcpf(M[k][k]);
    #pragma unroll
    for (int i = k+1; i < 4; ++i) {
      const float f = M[i][k] * inv;
      #pragma unroll
      for (int j = k+1; j < 6; ++j) M[i][j] = fmaf(-f, M[k][j], M[i][j]);
    }
  }
  const float i33 = __builtin_amdgcn_rcpf(M[3][3]);
  const float i22 = __builtin_amdgcn_rcpf(M[2][2]);
  const float i11 = __builtin_amdgcn_rcpf(M[1][1]);
  const float i00 = __builtin_amdgcn_rcpf(M[0][0]);
  const float a3 = M[3][4]*i33;
  const float b3 = M[3][5]*i33;
  const float a2 = fmaf(-M[2][3],a3,M[2][4])*i22;
  const float b2 = fmaf(-M[2][3],b3,M[2][5])*i22;
  const float a1 = fmaf(-M[1][3],a3,fmaf(-M[1][2],a2,M[1][4]))*i11;
  const float b1 = fmaf(-M[1][3],b3,fmaf(-M[1][2],b2,M[1][5]))*i11;
  const float a0 = fmaf(-M[0][3],a3,fmaf(-M[0][2],a2,fmaf(-M[0][1],a1,M[0][4])))*i00;
  const float b0 = fmaf(-M[0][3],b3,fmaf(-M[0][2],b2,fmaf(-M[0][1],b1,M[0][5])))*i00;
  s1 = make_float4(-a0,-a1,-a2,-a3);
  s2 = make_float4(-b0,-b1,-b2,-b3);
}

// Load F row i (16 floats) from global A/B with wave-uniform addresses (s_load).
template <bool F32>
__device__ __forceinline__ void load_frow(const float* Af, const float* Bf,
                                          const unsigned short* Ah, const unsigned short* Bh,
                                          int i, float* fr) {
  if (F32) {
    const float4 r0 = *(const float4*)(Af + i*12);
    const float4 r1 = *(const float4*)(Af + i*12 + 4);
    const float4 r2 = *(const float4*)(Af + i*12 + 8);
    const float4 rb = *(const float4*)(Bf + i*4);
    fr[0]=r0.x; fr[1]=r0.y; fr[2]=r0.z; fr[3]=r0.w;
    fr[4]=r1.x; fr[5]=r1.y; fr[6]=r1.z; fr[7]=r1.w;
    fr[8]=r2.x; fr[9]=r2.y; fr[10]=r2.z; fr[11]=r2.w;
    fr[12]=rb.x; fr[13]=rb.y; fr[14]=rb.z; fr[15]=rb.w;
  } else {
    const ushort4 h0 = *(const ushort4*)(Ah + i*12);
    const ushort4 h1 = *(const ushort4*)(Ah + i*12 + 4);
    const ushort4 h2 = *(const ushort4*)(Ah + i*12 + 8);
    const ushort4 hb = *(const ushort4*)(Bh + i*4);
    fr[0]=bf2f(h0.x); fr[1]=bf2f(h0.y); fr[2]=bf2f(h0.z); fr[3]=bf2f(h0.w);
    fr[4]=bf2f(h1.x); fr[5]=bf2f(h1.y); fr[6]=bf2f(h1.z); fr[7]=bf2f(h1.w);
    fr[8]=bf2f(h2.x); fr[9]=bf2f(h2.y); fr[10]=bf2f(h2.z); fr[11]=bf2f(h2.w);
    fr[12]=bf2f(hb.x); fr[13]=bf2f(hb.y); fr[14]=bf2f(hb.z); fr[15]=bf2f(hb.w);
  }
}

template <int MODE, bool F32>
__device__ __forceinline__ void backward_pass(
    const int c, const int b,
    const float* __restrict__ Af, const float* __restrict__ Bf,
    const unsigned short* __restrict__ Ah, const unsigned short* __restrict__ Bh,
    const float Qd, const float pc, const float* __restrict__ Fc,
    float* __restrict__ sUb, float* __restrict__ qtb, float* __restrict__ qub,
    float* __restrict__ vvb, float* __restrict__ gbl,
    float* __restrict__ wsf, unsigned short* __restrict__ wsh)
{
  float Vn[12];
  #pragma unroll
  for (int i = 0; i < 12; ++i) Vn[i] = 0.f;
  float vn = 0.f;

  for (int it = 0; it < TT; ++it) {
    // opaque SGPR zero: per-step uniform F loads, LICM blocked
    int zof = 0;
    __asm__ volatile("" : "+s"(zof));
    const float* Afo = Af + zof;
    const float* Bfo = Bf + zof;
    const unsigned short* Aho = Ah + zof;
    const unsigned short* Bho = Bh + zof;

    // publish v (from previous step) and compute qts = p[c] + F[:,c].v
    if (c < 12) vvb[c] = vn;
    __builtin_amdgcn_wave_barrier();
    float qts = pc;
    {
      const float4 v0 = *(const float4*)(vvb);
      const float4 v1 = *(const float4*)(vvb + 4);
      const float4 v2 = *(const float4*)(vvb + 8);
      qts = fmaf(Fc[0],v0.x,qts); qts = fmaf(Fc[1],v0.y,qts); qts = fmaf(Fc[2],v0.z,qts); qts = fmaf(Fc[3],v0.w,qts);
      qts = fmaf(Fc[4],v1.x,qts); qts = fmaf(Fc[5],v1.y,qts); qts = fmaf(Fc[6],v1.z,qts); qts = fmaf(Fc[7],v1.w,qts);
      qts = fmaf(Fc[8],v2.x,qts); qts = fmaf(Fc[9],v2.y,qts); qts = fmaf(Fc[10],v2.z,qts); qts = fmaf(Fc[11],v2.w,qts);
    }

    // U row c: U[a] = sum_j Vn[j]*F[j][a] — packed f32x2 (v_pk_fma_f32)
    f32x2 U2[8];
    #pragma unroll
    for (int k = 0; k < 8; ++k) U2[k] = (f32x2){0.f, 0.f};
    #pragma unroll
    for (int j = 0; j < 12; ++j) {
      float fr[16];
      load_frow<F32>(Afo, Bfo, Aho, Bho, j, fr);
      const f32x2 vj2 = {Vn[j], Vn[j]};
      #pragma unroll
      for (int k = 0; k < 8; ++k) {
        const f32x2 f2 = {fr[2*k], fr[2*k+1]};
        U2[k] = __builtin_elementwise_fma(f2, vj2, U2[k]);
      }
    }
    if (c < 12) {
      *(float4*)(sUb + c*US     ) = make_float4(U2[0].x,U2[0].y,U2[1].x,U2[1].y);
      *(float4*)(sUb + c*US +  4) = make_float4(U2[2].x,U2[2].y,U2[3].x,U2[3].y);
      *(float4*)(sUb + c*US +  8) = make_float4(U2[4].x,U2[4].y,U2[5].x,U2[5].y);
      *(float4*)(sUb + c*US + 12) = make_float4(U2[6].x,U2[6].y,U2[7].x,U2[7].y);
    }
    __builtin_amdgcn_wave_barrier();

    // read U column c (12 strided b32, per-lane addresses)
    float Uc[12];
    #pragma unroll
    for (int i = 0; i < 12; ++i) Uc[i] = sUb[i*US + c];

    // qtc[a] = sum_i F[i][a]*U[i][c] — packed; diag added after (R7 semantics)
    f32x2 qt2[8];
    #pragma unroll
    for (int k = 0; k < 8; ++k) qt2[k] = (f32x2){0.f, 0.f};
    #pragma unroll
    for (int i = 0; i < 12; ++i) {
      float fr[16];
      load_frow<F32>(Afo, Bfo, Aho, Bho, i, fr);
      const f32x2 ui2 = {Uc[i], Uc[i]};
      #pragma unroll
      for (int k = 0; k < 8; ++k) {
        const f32x2 f2 = {fr[2*k], fr[2*k+1]};
        qt2[k] = __builtin_elementwise_fma(f2, ui2, qt2[k]);
      }
    }
    float qtc[16];
    #pragma unroll
    for (int a = 0; a < 16; ++a) {
      qtc[a] = (a & 1) ? qt2[a>>1].y : qt2[a>>1].x;
      qtc[a] += (a == c) ? Qd : 0.f;
    }

    // publish cols 12..15 (Quu rows + Qxu cols) and qu
    if (c >= 12) {
      float* qa = qtb + (c-12)*QS;
      *(float4*)(qa     ) = make_float4(qtc[0],qtc[1],qtc[2],qtc[3]);
      *(float4*)(qa +  4) = make_float4(qtc[4],qtc[5],qtc[6],qtc[7]);
      *(float4*)(qa +  8) = make_float4(qtc[8],qtc[9],qtc[10],qtc[11]);
      *(float4*)(qa + 12) = make_float4(qtc[12],qtc[13],qtc[14],qtc[15]);
      qub[c-12] = qts;
    }
    __builtin_amdgcn_wave_barrier();

    const float4 q0 = *(const float4*)(qtb + 0*QS + 12);
    const float4 q1 = *(const float4*)(qtb + 1*QS + 12);
    const float4 q2 = *(const float4*)(qtb + 2*QS + 12);
    const float4 q3 = *(const float4*)(qtb + 3*QS + 12);
    const float4 quv = *(const float4*)(qub);

    float4 Kc, kf;
    lu46(q0,q1,q2,q3, make_float4(qtc[12],qtc[13],qtc[14],qtc[15]), quv, Kc, kf);

    // store gains: [t][b][col 0..12][4], col 12 = kff; t = TT-1-it
    if (c < 13) {
      float4 gw;
      gw.x = (c < 12) ? Kc.x : kf.x;
      gw.y = (c < 12) ? Kc.y : kf.y;
      gw.z = (c < 12) ? Kc.z : kf.z;
      gw.w = (c < 12) ? Kc.w : kf.w;
      if (MODE == 2) {
        *(float4*)(gbl + (TT-1-it)*52 + c*4) = gw;
      } else {
        const size_t off = ((size_t)(TT-1-it)*NBB + b)*52 + (size_t)c*4;
        if (MODE == 1) {
          ushort4 us;
          us.x = f2bf(gw.x); us.y = f2bf(gw.y); us.z = f2bf(gw.z); us.w = f2bf(gw.w);
          *(ushort4*)(wsh + off) = us;
        } else {
          *(float4*)(wsf + off) = gw;
        }
      }
    }

    // Vn[:,c] = Qxx[:,c] + Qxu*K[:,c] — packed
    f32x2 Vn2[6];
    #pragma unroll
    for (int k = 0; k < 6; ++k) Vn2[k] = (f32x2){qtc[2*k], qtc[2*k+1]};
    #pragma unroll
    for (int u = 0; u < 4; ++u) {
      const float ku = (u==0)?Kc.x:((u==1)?Kc.y:((u==2)?Kc.z:Kc.w));
      const f32x2 ku2 = {ku, ku};
      const float4 a0 = *(const float4*)(qtb + u*QS);
      const float4 a1 = *(const float4*)(qtb + u*QS + 4);
      const float4 a2 = *(const float4*)(qtb + u*QS + 8);
      Vn2[0] = __builtin_elementwise_fma((f32x2){a0.x,a0.y}, ku2, Vn2[0]);
      Vn2[1] = __builtin_elementwise_fma((f32x2){a0.z,a0.w}, ku2, Vn2[1]);
      Vn2[2] = __builtin_elementwise_fma((f32x2){a1.x,a1.y}, ku2, Vn2[2]);
      Vn2[3] = __builtin_elementwise_fma((f32x2){a1.z,a1.w}, ku2, Vn2[3]);
      Vn2[4] = __builtin_elementwise_fma((f32x2){a2.x,a2.y}, ku2, Vn2[4]);
      Vn2[5] = __builtin_elementwise_fma((f32x2){a2.z,a2.w}, ku2, Vn2[5]);
    }
    #pragma unroll
    for (int i = 0; i < 12; ++i) Vn[i] = (i & 1) ? Vn2[i>>1].y : Vn2[i>>1].x;

    // vn = qts + Qxu[c,:].kff  (Qxu[c,u] = qtc[12+u] by symmetry)
    vn = qts;
    vn = fmaf(qtc[12],kf.x,vn); vn = fmaf(qtc[13],kf.y,vn);
    vn = fmaf(qtc[14],kf.z,vn); vn = fmaf(qtc[15],kf.w,vn);
    __builtin_amdgcn_wave_barrier();
  }
}

// MODE: 0 = f32 gains in d_ws, 1 = bf16 gains in d_ws, 2 = gains in LDS
template <int MODE>
__global__ __launch_bounds__(64, 2) void mpc_kernel(
    const void* __restrict__ x_init, const void* __restrict__ Qm,
    const void* __restrict__ pm, const void* __restrict__ Am,
    const void* __restrict__ Bm, void* __restrict__ outv,
    void* __restrict__ wsv)
{
  __shared__ float sF[192];     // col-major (Fc init only)
  __shared__ float sFr[320];    // row-major stride 20 (forward pass)
  __shared__ float sU[4*UES];   // per-elem U, rows stride US
  __shared__ float sQt[4*QTE];  // per-elem Qt cols 12..15
  __shared__ float squ[4*20];
  __shared__ float svv[4*20];
  __shared__ float sx[4*20];
  __shared__ float sG[(MODE == 2) ? (4*2600) : 4];

  const int tid = threadIdx.x;
  const int c = tid & 15;
  const int g = tid >> 4;
  const int b = (int)blockIdx.x * 4 + g;

  // ---- runtime dtype detection (wave-uniform) ----
  bool isf32;
  {
    const unsigned int* aw = (const unsigned int*)Am;
    int insane = 0;
    #pragma unroll 4
    for (int k = 0; k < 72; ++k) {
      const unsigned int w = aw[k];
      const unsigned short h0 = (unsigned short)(w & 0xFFFFu);
      const unsigned short h1 = (unsigned short)(w >> 16);
      const int e0 = (h0 >> 7) & 0xFF, e1 = (h1 >> 7) & 0xFF;
      insane += (((h0 & 0x7FFF) != 0) && (e0 < 107 || e0 > 132)) ? 1 : 0;
      insane += (((h1 & 0x7FFF) != 0) && (e1 < 107 || e1 > 132)) ? 1 : 0;
    }
    isf32 = (insane > 8);
  }

  const float* const xf = (const float*)x_init;
  const float* const Qf = (const float*)Qm;
  const float* const pf = (const float*)pm;
  const float* const Af = (const float*)Am;
  const float* const Bf = (const float*)Bm;
  const unsigned short* const xh = (const unsigned short*)x_init;
  const unsigned short* const Qh = (const unsigned short*)Qm;
  const unsigned short* const ph = (const unsigned short*)pm;
  const unsigned short* const Ah = (const unsigned short*)Am;
  const unsigned short* const Bh = (const unsigned short*)Bm;

  // ---- stage F (Fc + forward rows); zero v ----
  for (int idx = tid; idx < 320; idx += 64) {
    const int i_ = idx / 20, a_ = idx - i_ * 20;
    float fv = 0.f;
    if (i_ < 12 && a_ < 16) {
      if (a_ < 12) fv = isf32 ? Af[i_*12 + a_] : bf2f(Ah[i_*12 + a_]);
      else         fv = isf32 ? Bf[i_*4 + (a_-12)] : bf2f(Bh[i_*4 + (a_-12)]);
    }
    sFr[idx] = fv;
  }
  for (int idx = tid; idx < 192; idx += 64) {
    const int a_ = idx / 12, i_ = idx - a_ * 12;
    float fv;
    if (a_ < 12) fv = isf32 ? Af[i_*12 + a_] : bf2f(Ah[i_*12 + a_]);
    else         fv = isf32 ? Bf[i_*4 + (a_-12)] : bf2f(Bh[i_*4 + (a_-12)]);
    sF[idx] = fv;
  }
  for (int idx = tid; idx < 4*20; idx += 64) svv[idx] = 0.f;
  __syncthreads();

  float Fc[12];
  #pragma unroll
  for (int i = 0; i < 12; ++i) Fc[i] = sF[c*12 + i];
  const float Qd = isf32 ? Qf[b*16 + c] : bf2f(Qh[b*16 + c]);
  const float pc = isf32 ? pf[b*16 + c] : bf2f(ph[b*16 + c]);

  float* const sUb = &sU[g*UES];
  float* const qtb = &sQt[g*QTE];
  float* const qub = &squ[g*20];
  float* const vvb = &svv[g*20];
  float* const sxg = &sx[g*20];
  float* const gbl = (MODE == 2) ? &sG[g*2600] : nullptr;

  float* const wsf = (float*)wsv;
  unsigned short* const wsh = (unsigned short*)wsv;

  if (isf32) {
    backward_pass<MODE, true >(c, b, Af, Bf, Ah, Bh, Qd, pc, Fc, sUb, qtb, qub, vvb, gbl, wsf, wsh);
  } else {
    backward_pass<MODE, false>(c, b, Af, Bf, Ah, Bh, Qd, pc, Fc, sUb, qtb, qub, vvb, gbl, wsf, wsh);
  }

  // ----------------- forward rollout (R7 verbatim) -----------------
  if (MODE != 2) __threadfence();  // drain own gain stores before reading back

  float xc = 0.f;
  if (c < 12) xc = isf32 ? xf[b*12 + c] : bf2f(xh[b*12 + c]);

  float* const outf = (float*)outv;
  unsigned short* const outh = (unsigned short*)outv;

  auto loadg = [&](int t) -> float4 {
    if (c >= 13) return make_float4(0.f,0.f,0.f,0.f);
    if (MODE == 2) return *(const float4*)(gbl + t*52 + c*4);
    const size_t off = ((size_t)t*NBB + b)*52 + (size_t)c*4;
    if (MODE == 1) {
      const ushort4 us = *(const ushort4*)(wsh + off);
      return make_float4(bf2f(us.x),bf2f(us.y),bf2f(us.z),bf2f(us.w));
    }
    return *(const float4*)(wsf + off);
  };

  float4 gv = loadg(0);

  for (int t = 0; t < TT; ++t) {
    if (c < 12) sxg[c] = xc;
    __builtin_amdgcn_wave_barrier();
    const float4 x0 = *(const float4*)(sxg);
    const float4 x1 = *(const float4*)(sxg + 4);
    const float4 x2 = *(const float4*)(sxg + 8);

    const float s = (c < 12) ? xc : 1.0f;
    const float u0 = rrsum16(gv.x*s), u1 = rrsum16(gv.y*s), u2 = rrsum16(gv.z*s), u3 = rrsum16(gv.w*s);

    if (c == 0) {
      const size_t o4 = ((size_t)t*NBB + b)*4;
      if (isf32) {
        *(float4*)(outf + o4) = make_float4(u0,u1,u2,u3);
      } else {
        ushort4 us;
        us.x = f2bf(u0); us.y = f2bf(u1); us.z = f2bf(u2); us.w = f2bf(u3);
        *(ushort4*)(outh + o4) = us;
      }
    }

    float4 gn = make_float4(0,0,0,0);
    if (t + 1 < TT) gn = loadg(t+1);

    const float4 fr0 = *(const float4*)(sFr + c*20);
    const float4 fr1 = *(const float4*)(sFr + c*20 + 4);
    const float4 fr2 = *(const float4*)(sFr + c*20 + 8);
    const float4 frB = *(const float4*)(sFr + c*20 + 12);
    float xp = fr0.x*x0.x;
    xp = fmaf(fr0.y,x0.y,xp); xp = fmaf(fr0.z,x0.z,xp); xp = fmaf(fr0.w,x0.w,xp);
    xp = fmaf(fr1.x,x1.x,xp); xp = fmaf(fr1.y,x1.y,xp); xp = fmaf(fr1.z,x1.z,xp); xp = fmaf(fr1.w,x1.w,xp);
    xp = fmaf(fr2.x,x2.x,xp); xp = fmaf(fr2.y,x2.y,xp); xp = fmaf(fr2.z,x2.z,xp); xp = fmaf(fr2.w,x2.w,xp);
    xp = fmaf(frB.x,u0,xp); xp = fmaf(frB.y,u1,xp); xp = fmaf(frB.z,u2,xp); xp = fmaf(frB.w,u3,xp);
    xc = xp;
    gv = gn;
  }
}

extern "C" void kernel_launch(void* const* d_in, const int* in_sizes, int n_in,
                              void* d_out, int out_size, void* d_ws, size_t ws_size,
                              hipStream_t stream) {
  (void)in_sizes; (void)n_in; (void)out_size;
  const size_t needF = (size_t)TT * NBB * 52 * sizeof(float);          // 85.2 MB
  const size_t needH = (size_t)TT * NBB * 52 * sizeof(unsigned short); // 42.6 MB
  dim3 grid(NBB / 4), block(64);
  if (d_ws != nullptr && ws_size >= needF) {
    mpc_kernel<0><<<grid, block, 0, stream>>>(d_in[0], d_in[1], d_in[2], d_in[3], d_in[4], d_out, d_ws);
  } else if (d_ws != nullptr && ws_size >= needH) {
    mpc_kernel<1><<<grid, block, 0, stream>>>(d_in[0], d_in[1], d_in[2], d_in[3], d_in[4], d_out, d_ws);
  } else {
    mpc_kernel<2><<<grid, block, 0, stream>>>(d_in[0], d_in[1], d_in[2], d_in[3], d_in[4], d_out, d_ws);
  }
}

// Round 11
// 232.674 us; speedup vs baseline: 1.3280x; 1.0021x over previous
//
#include <hip/hip_runtime.h>
#include <hip/hip_bf16.h>

// LQR-MPC: T=50, N=12, M=4, NSC=16, NB=8192.
// == R10 (validated 186us) + ONE change: forward rollout uses a depth-2
// gain-prefetch register ring (unroll-2) to hide the ~200cyc L2/L3 gain-load
// latency. Backward pass byte-identical to R10.
// CHOLESKY BANNED (NaN R1/R8/R9); LU validated R3-R7/R10.
// U-SCHEME: lane c holds Vn[:,c] (= V row c by symmetry) in registers;
// U row c = V[c,:]*F from s_load F rows (scalar path). One 16x16 U
// transpose via LDS per step. Single-wave blocks: DS in-order ->
// wave_barrier(). Vn = Qxx + Qxu*K exactly (K^T Qux + K^T Quu K cancels).
#define TT 50
#define NBB 8192
#define QS  20    // Qt col stride (floats)
#define QTE 88    // Qt per-elem stride
#define US  20    // U row stride (floats)
#define UES 248   // U per-elem stride (248%32=24 -> staggered banks)

typedef float f32x2 __attribute__((ext_vector_type(2)));

__device__ __forceinline__ unsigned short f2bf(float f) {
  unsigned int u = __float_as_uint(f);
  u = (u + 0x7FFFu + ((u >> 16) & 1u)) >> 16;   // RNE
  return (unsigned short)u;
}
__device__ __forceinline__ float bf2f(unsigned short h) {
  return __uint_as_float(((unsigned int)h) << 16);
}
__device__ __forceinline__ float rrsum16(float v) {
  int t;
  t = __builtin_amdgcn_update_dpp(0, __float_as_int(v), 0x128, 0xF, 0xF, true); v += __int_as_float(t);
  t = __builtin_amdgcn_update_dpp(0, __float_as_int(v), 0x124, 0xF, 0xF, true); v += __int_as_float(t);
  t = __builtin_amdgcn_update_dpp(0, __float_as_int(v), 0x122, 0xF, 0xF, true); v += __int_as_float(t);
  t = __builtin_amdgcn_update_dpp(0, __float_as_int(v), 0x121, 0xF, 0xF, true); v += __int_as_float(t);
  return v;
}

// Branchless partial-pivot LU on [Quu | r1 | r2]; s1 = -Quu^-1 r1, s2 = -Quu^-1 r2
__device__ __forceinline__ void lu46(const float4 q0, const float4 q1, const float4 q2, const float4 q3,
                                     const float4 r1, const float4 r2, float4& s1, float4& s2) {
  float M[4][6];
  M[0][0]=q0.x; M[1][0]=q0.y; M[2][0]=q0.z; M[3][0]=q0.w;
  M[0][1]=q1.x; M[1][1]=q1.y; M[2][1]=q1.z; M[3][1]=q1.w;
  M[0][2]=q2.x; M[1][2]=q2.y; M[2][2]=q2.z; M[3][2]=q2.w;
  M[0][3]=q3.x; M[1][3]=q3.y; M[2][3]=q3.z; M[3][3]=q3.w;
  M[0][4]=r1.x; M[1][4]=r1.y; M[2][4]=r1.z; M[3][4]=r1.w;
  M[0][5]=r2.x; M[1][5]=r2.y; M[2][5]=r2.z; M[3][5]=r2.w;
  #pragma unroll
  for (int k = 0; k < 4; ++k) {
    #pragma unroll
    for (int i = k+1; i < 4; ++i) {
      const bool sw = fabsf(M[i][k]) > fabsf(M[k][k]);
      #pragma unroll
      for (int j = 0; j < 6; ++j) {
        const float a_ = M[k][j], b_ = M[i][j];
        M[k][j] = sw ? b_ : a_;
        M[i][j] = sw ? a_ : b_;
      }
    }
    const float inv = __builtin_amdgcn_rcpf(M[k][k]);
    #pragma unroll
    for (int i = k+1; i < 4; ++i) {
      const float f = M[i][k] * inv;
      #pragma unroll
      for (int j = k+1; j < 6; ++j) M[i][j] = fmaf(-f, M[k][j], M[i][j]);
    }
  }
  const float i33 = __builtin_amdgcn_rcpf(M[3][3]);
  const float i22 = __builtin_amdgcn_rcpf(M[2][2]);
  const float i11 = __builtin_amdgcn_rcpf(M[1][1]);
  const float i00 = __builtin_amdgcn_rcpf(M[0][0]);
  const float a3 = M[3][4]*i33;
  const float b3 = M[3][5]*i33;
  const float a2 = fmaf(-M[2][3],a3,M[2][4])*i22;
  const float b2 = fmaf(-M[2][3],b3,M[2][5])*i22;
  const float a1 = fmaf(-M[1][3],a3,fmaf(-M[1][2],a2,M[1][4]))*i11;
  const float b1 = fmaf(-M[1][3],b3,fmaf(-M[1][2],b2,M[1][5]))*i11;
  const float a0 = fmaf(-M[0][3],a3,fmaf(-M[0][2],a2,fmaf(-M[0][1],a1,M[0][4])))*i00;
  const float b0 = fmaf(-M[0][3],b3,fmaf(-M[0][2],b2,fmaf(-M[0][1],b1,M[0][5])))*i00;
  s1 = make_float4(-a0,-a1,-a2,-a3);
  s2 = make_float4(-b0,-b1,-b2,-b3);
}

// Load F row i (16 floats) from global A/B with wave-uniform addresses (s_load).
template <bool F32>
__device__ __forceinline__ void load_frow(const float* Af, const float* Bf,
                                          const unsigned short* Ah, const unsigned short* Bh,
                                          int i, float* fr) {
  if (F32) {
    const float4 r0 = *(const float4*)(Af + i*12);
    const float4 r1 = *(const float4*)(Af + i*12 + 4);
    const float4 r2 = *(const float4*)(Af + i*12 + 8);
    const float4 rb = *(const float4*)(Bf + i*4);
    fr[0]=r0.x; fr[1]=r0.y; fr[2]=r0.z; fr[3]=r0.w;
    fr[4]=r1.x; fr[5]=r1.y; fr[6]=r1.z; fr[7]=r1.w;
    fr[8]=r2.x; fr[9]=r2.y; fr[10]=r2.z; fr[11]=r2.w;
    fr[12]=rb.x; fr[13]=rb.y; fr[14]=rb.z; fr[15]=rb.w;
  } else {
    const ushort4 h0 = *(const ushort4*)(Ah + i*12);
    const ushort4 h1 = *(const ushort4*)(Ah + i*12 + 4);
    const ushort4 h2 = *(const ushort4*)(Ah + i*12 + 8);
    const ushort4 hb = *(const ushort4*)(Bh + i*4);
    fr[0]=bf2f(h0.x); fr[1]=bf2f(h0.y); fr[2]=bf2f(h0.z); fr[3]=bf2f(h0.w);
    fr[4]=bf2f(h1.x); fr[5]=bf2f(h1.y); fr[6]=bf2f(h1.z); fr[7]=bf2f(h1.w);
    fr[8]=bf2f(h2.x); fr[9]=bf2f(h2.y); fr[10]=bf2f(h2.z); fr[11]=bf2f(h2.w);
    fr[12]=bf2f(hb.x); fr[13]=bf2f(hb.y); fr[14]=bf2f(hb.z); fr[15]=bf2f(hb.w);
  }
}

template <int MODE, bool F32>
__device__ __forceinline__ void backward_pass(
    const int c, const int b,
    const float* __restrict__ Af, const float* __restrict__ Bf,
    const unsigned short* __restrict__ Ah, const unsigned short* __restrict__ Bh,
    const float Qd, const float pc, const float* __restrict__ Fc,
    float* __restrict__ sUb, float* __restrict__ qtb, float* __restrict__ qub,
    float* __restrict__ vvb, float* __restrict__ gbl,
    float* __restrict__ wsf, unsigned short* __restrict__ wsh)
{
  float Vn[12];
  #pragma unroll
  for (int i = 0; i < 12; ++i) Vn[i] = 0.f;
  float vn = 0.f;

  for (int it = 0; it < TT; ++it) {
    // opaque SGPR zero: per-step uniform F loads, LICM blocked
    int zof = 0;
    __asm__ volatile("" : "+s"(zof));
    const float* Afo = Af + zof;
    const float* Bfo = Bf + zof;
    const unsigned short* Aho = Ah + zof;
    const unsigned short* Bho = Bh + zof;

    // publish v (from previous step) and compute qts = p[c] + F[:,c].v
    if (c < 12) vvb[c] = vn;
    __builtin_amdgcn_wave_barrier();
    float qts = pc;
    {
      const float4 v0 = *(const float4*)(vvb);
      const float4 v1 = *(const float4*)(vvb + 4);
      const float4 v2 = *(const float4*)(vvb + 8);
      qts = fmaf(Fc[0],v0.x,qts); qts = fmaf(Fc[1],v0.y,qts); qts = fmaf(Fc[2],v0.z,qts); qts = fmaf(Fc[3],v0.w,qts);
      qts = fmaf(Fc[4],v1.x,qts); qts = fmaf(Fc[5],v1.y,qts); qts = fmaf(Fc[6],v1.z,qts); qts = fmaf(Fc[7],v1.w,qts);
      qts = fmaf(Fc[8],v2.x,qts); qts = fmaf(Fc[9],v2.y,qts); qts = fmaf(Fc[10],v2.z,qts); qts = fmaf(Fc[11],v2.w,qts);
    }

    // U row c: U[a] = sum_j Vn[j]*F[j][a] — packed f32x2 (v_pk_fma_f32)
    f32x2 U2[8];
    #pragma unroll
    for (int k = 0; k < 8; ++k) U2[k] = (f32x2){0.f, 0.f};
    #pragma unroll
    for (int j = 0; j < 12; ++j) {
      float fr[16];
      load_frow<F32>(Afo, Bfo, Aho, Bho, j, fr);
      const f32x2 vj2 = {Vn[j], Vn[j]};
      #pragma unroll
      for (int k = 0; k < 8; ++k) {
        const f32x2 f2 = {fr[2*k], fr[2*k+1]};
        U2[k] = __builtin_elementwise_fma(f2, vj2, U2[k]);
      }
    }
    if (c < 12) {
      *(float4*)(sUb + c*US     ) = make_float4(U2[0].x,U2[0].y,U2[1].x,U2[1].y);
      *(float4*)(sUb + c*US +  4) = make_float4(U2[2].x,U2[2].y,U2[3].x,U2[3].y);
      *(float4*)(sUb + c*US +  8) = make_float4(U2[4].x,U2[4].y,U2[5].x,U2[5].y);
      *(float4*)(sUb + c*US + 12) = make_float4(U2[6].x,U2[6].y,U2[7].x,U2[7].y);
    }
    __builtin_amdgcn_wave_barrier();

    // read U column c (12 strided b32, per-lane addresses)
    float Uc[12];
    #pragma unroll
    for (int i = 0; i < 12; ++i) Uc[i] = sUb[i*US + c];

    // qtc[a] = sum_i F[i][a]*U[i][c] — packed; diag added after
    f32x2 qt2[8];
    #pragma unroll
    for (int k = 0; k < 8; ++k) qt2[k] = (f32x2){0.f, 0.f};
    #pragma unroll
    for (int i = 0; i < 12; ++i) {
      float fr[16];
      load_frow<F32>(Afo, Bfo, Aho, Bho, i, fr);
      const f32x2 ui2 = {Uc[i], Uc[i]};
      #pragma unroll
      for (int k = 0; k < 8; ++k) {
        const f32x2 f2 = {fr[2*k], fr[2*k+1]};
        qt2[k] = __builtin_elementwise_fma(f2, ui2, qt2[k]);
      }
    }
    float qtc[16];
    #pragma unroll
    for (int a = 0; a < 16; ++a) {
      qtc[a] = (a & 1) ? qt2[a>>1].y : qt2[a>>1].x;
      qtc[a] += (a == c) ? Qd : 0.f;
    }

    // publish cols 12..15 (Quu rows + Qxu cols) and qu
    if (c >= 12) {
      float* qa = qtb + (c-12)*QS;
      *(float4*)(qa     ) = make_float4(qtc[0],qtc[1],qtc[2],qtc[3]);
      *(float4*)(qa +  4) = make_float4(qtc[4],qtc[5],qtc[6],qtc[7]);
      *(float4*)(qa +  8) = make_float4(qtc[8],qtc[9],qtc[10],qtc[11]);
      *(float4*)(qa + 12) = make_float4(qtc[12],qtc[13],qtc[14],qtc[15]);
      qub[c-12] = qts;
    }
    __builtin_amdgcn_wave_barrier();

    const float4 q0 = *(const float4*)(qtb + 0*QS + 12);
    const float4 q1 = *(const float4*)(qtb + 1*QS + 12);
    const float4 q2 = *(const float4*)(qtb + 2*QS + 12);
    const float4 q3 = *(const float4*)(qtb + 3*QS + 12);
    const float4 quv = *(const float4*)(qub);

    float4 Kc, kf;
    lu46(q0,q1,q2,q3, make_float4(qtc[12],qtc[13],qtc[14],qtc[15]), quv, Kc, kf);

    // store gains: [t][b][col 0..12][4], col 12 = kff; t = TT-1-it
    if (c < 13) {
      float4 gw;
      gw.x = (c < 12) ? Kc.x : kf.x;
      gw.y = (c < 12) ? Kc.y : kf.y;
      gw.z = (c < 12) ? Kc.z : kf.z;
      gw.w = (c < 12) ? Kc.w : kf.w;
      if (MODE == 2) {
        *(float4*)(gbl + (TT-1-it)*52 + c*4) = gw;
      } else {
        const size_t off = ((size_t)(TT-1-it)*NBB + b)*52 + (size_t)c*4;
        if (MODE == 1) {
          ushort4 us;
          us.x = f2bf(gw.x); us.y = f2bf(gw.y); us.z = f2bf(gw.z); us.w = f2bf(gw.w);
          *(ushort4*)(wsh + off) = us;
        } else {
          *(float4*)(wsf + off) = gw;
        }
      }
    }

    // Vn[:,c] = Qxx[:,c] + Qxu*K[:,c] — packed
    f32x2 Vn2[6];
    #pragma unroll
    for (int k = 0; k < 6; ++k) Vn2[k] = (f32x2){qtc[2*k], qtc[2*k+1]};
    #pragma unroll
    for (int u = 0; u < 4; ++u) {
      const float ku = (u==0)?Kc.x:((u==1)?Kc.y:((u==2)?Kc.z:Kc.w));
      const f32x2 ku2 = {ku, ku};
      const float4 a0 = *(const float4*)(qtb + u*QS);
      const float4 a1 = *(const float4*)(qtb + u*QS + 4);
      const float4 a2 = *(const float4*)(qtb + u*QS + 8);
      Vn2[0] = __builtin_elementwise_fma((f32x2){a0.x,a0.y}, ku2, Vn2[0]);
      Vn2[1] = __builtin_elementwise_fma((f32x2){a0.z,a0.w}, ku2, Vn2[1]);
      Vn2[2] = __builtin_elementwise_fma((f32x2){a1.x,a1.y}, ku2, Vn2[2]);
      Vn2[3] = __builtin_elementwise_fma((f32x2){a1.z,a1.w}, ku2, Vn2[3]);
      Vn2[4] = __builtin_elementwise_fma((f32x2){a2.x,a2.y}, ku2, Vn2[4]);
      Vn2[5] = __builtin_elementwise_fma((f32x2){a2.z,a2.w}, ku2, Vn2[5]);
    }
    #pragma unroll
    for (int i = 0; i < 12; ++i) Vn[i] = (i & 1) ? Vn2[i>>1].y : Vn2[i>>1].x;

    // vn = qts + Qxu[c,:].kff  (Qxu[c,u] = qtc[12+u] by symmetry)
    vn = qts;
    vn = fmaf(qtc[12],kf.x,vn); vn = fmaf(qtc[13],kf.y,vn);
    vn = fmaf(qtc[14],kf.z,vn); vn = fmaf(qtc[15],kf.w,vn);
    __builtin_amdgcn_wave_barrier();
  }
}

// MODE: 0 = f32 gains in d_ws, 1 = bf16 gains in d_ws, 2 = gains in LDS
template <int MODE>
__global__ __launch_bounds__(64, 2) void mpc_kernel(
    const void* __restrict__ x_init, const void* __restrict__ Qm,
    const void* __restrict__ pm, const void* __restrict__ Am,
    const void* __restrict__ Bm, void* __restrict__ outv,
    void* __restrict__ wsv)
{
  __shared__ float sF[192];     // col-major (Fc init only)
  __shared__ float sFr[320];    // row-major stride 20 (forward pass)
  __shared__ float sU[4*UES];   // per-elem U, rows stride US
  __shared__ float sQt[4*QTE];  // per-elem Qt cols 12..15
  __shared__ float squ[4*20];
  __shared__ float svv[4*20];
  __shared__ float sx[4*20];
  __shared__ float sG[(MODE == 2) ? (4*2600) : 4];

  const int tid = threadIdx.x;
  const int c = tid & 15;
  const int g = tid >> 4;
  const int b = (int)blockIdx.x * 4 + g;

  // ---- runtime dtype detection (wave-uniform) ----
  bool isf32;
  {
    const unsigned int* aw = (const unsigned int*)Am;
    int insane = 0;
    #pragma unroll 4
    for (int k = 0; k < 72; ++k) {
      const unsigned int w = aw[k];
      const unsigned short h0 = (unsigned short)(w & 0xFFFFu);
      const unsigned short h1 = (unsigned short)(w >> 16);
      const int e0 = (h0 >> 7) & 0xFF, e1 = (h1 >> 7) & 0xFF;
      insane += (((h0 & 0x7FFF) != 0) && (e0 < 107 || e0 > 132)) ? 1 : 0;
      insane += (((h1 & 0x7FFF) != 0) && (e1 < 107 || e1 > 132)) ? 1 : 0;
    }
    isf32 = (insane > 8);
  }

  const float* const xf = (const float*)x_init;
  const float* const Qf = (const float*)Qm;
  const float* const pf = (const float*)pm;
  const float* const Af = (const float*)Am;
  const float* const Bf = (const float*)Bm;
  const unsigned short* const xh = (const unsigned short*)x_init;
  const unsigned short* const Qh = (const unsigned short*)Qm;
  const unsigned short* const ph = (const unsigned short*)pm;
  const unsigned short* const Ah = (const unsigned short*)Am;
  const unsigned short* const Bh = (const unsigned short*)Bm;

  // ---- stage F (Fc + forward rows); zero v ----
  for (int idx = tid; idx < 320; idx += 64) {
    const int i_ = idx / 20, a_ = idx - i_ * 20;
    float fv = 0.f;
    if (i_ < 12 && a_ < 16) {
      if (a_ < 12) fv = isf32 ? Af[i_*12 + a_] : bf2f(Ah[i_*12 + a_]);
      else         fv = isf32 ? Bf[i_*4 + (a_-12)] : bf2f(Bh[i_*4 + (a_-12)]);
    }
    sFr[idx] = fv;
  }
  for (int idx = tid; idx < 192; idx += 64) {
    const int a_ = idx / 12, i_ = idx - a_ * 12;
    float fv;
    if (a_ < 12) fv = isf32 ? Af[i_*12 + a_] : bf2f(Ah[i_*12 + a_]);
    else         fv = isf32 ? Bf[i_*4 + (a_-12)] : bf2f(Bh[i_*4 + (a_-12)]);
    sF[idx] = fv;
  }
  for (int idx = tid; idx < 4*20; idx += 64) svv[idx] = 0.f;
  __syncthreads();

  float Fc[12];
  #pragma unroll
  for (int i = 0; i < 12; ++i) Fc[i] = sF[c*12 + i];
  const float Qd = isf32 ? Qf[b*16 + c] : bf2f(Qh[b*16 + c]);
  const float pc = isf32 ? pf[b*16 + c] : bf2f(ph[b*16 + c]);

  float* const sUb = &sU[g*UES];
  float* const qtb = &sQt[g*QTE];
  float* const qub = &squ[g*20];
  float* const vvb = &svv[g*20];
  float* const sxg = &sx[g*20];
  float* const gbl = (MODE == 2) ? &sG[g*2600] : nullptr;

  float* const wsf = (float*)wsv;
  unsigned short* const wsh = (unsigned short*)wsv;

  if (isf32) {
    backward_pass<MODE, true >(c, b, Af, Bf, Ah, Bh, Qd, pc, Fc, sUb, qtb, qub, vvb, gbl, wsf, wsh);
  } else {
    backward_pass<MODE, false>(c, b, Af, Bf, Ah, Bh, Qd, pc, Fc, sUb, qtb, qub, vvb, gbl, wsf, wsh);
  }

  // ----------------- forward rollout: depth-2 gain prefetch ring -----------------
  if (MODE != 2) __threadfence();  // drain own gain stores before reading back

  float xc = 0.f;
  if (c < 12) xc = isf32 ? xf[b*12 + c] : bf2f(xh[b*12 + c]);

  float* const outf = (float*)outv;
  unsigned short* const outh = (unsigned short*)outv;

  auto loadg = [&](int t) -> float4 {
    if (c >= 13) return make_float4(0.f,0.f,0.f,0.f);
    if (MODE == 2) return *(const float4*)(gbl + t*52 + c*4);
    const size_t off = ((size_t)t*NBB + b)*52 + (size_t)c*4;
    if (MODE == 1) {
      const ushort4 us = *(const ushort4*)(wsh + off);
      return make_float4(bf2f(us.x),bf2f(us.y),bf2f(us.z),bf2f(us.w));
    }
    return *(const float4*)(wsf + off);
  };

  auto body = [&](int t, const float4 gv) {
    if (c < 12) sxg[c] = xc;
    __builtin_amdgcn_wave_barrier();
    const float4 x0 = *(const float4*)(sxg);
    const float4 x1 = *(const float4*)(sxg + 4);
    const float4 x2 = *(const float4*)(sxg + 8);

    const float s = (c < 12) ? xc : 1.0f;
    const float u0 = rrsum16(gv.x*s), u1 = rrsum16(gv.y*s), u2 = rrsum16(gv.z*s), u3 = rrsum16(gv.w*s);

    if (c == 0) {
      const size_t o4 = ((size_t)t*NBB + b)*4;
      if (isf32) {
        *(float4*)(outf + o4) = make_float4(u0,u1,u2,u3);
      } else {
        ushort4 us;
        us.x = f2bf(u0); us.y = f2bf(u1); us.z = f2bf(u2); us.w = f2bf(u3);
        *(ushort4*)(outh + o4) = us;
      }
    }
    const float4 fr0 = *(const float4*)(sFr + c*20);
    const float4 fr1 = *(const float4*)(sFr + c*20 + 4);
    const float4 fr2 = *(const float4*)(sFr + c*20 + 8);
    const float4 frB = *(const float4*)(sFr + c*20 + 12);
    float xp = fr0.x*x0.x;
    xp = fmaf(fr0.y,x0.y,xp); xp = fmaf(fr0.z,x0.z,xp); xp = fmaf(fr0.w,x0.w,xp);
    xp = fmaf(fr1.x,x1.x,xp); xp = fmaf(fr1.y,x1.y,xp); xp = fmaf(fr1.z,x1.z,xp); xp = fmaf(fr1.w,x1.w,xp);
    xp = fmaf(fr2.x,x2.x,xp); xp = fmaf(fr2.y,x2.y,xp); xp = fmaf(fr2.z,x2.z,xp); xp = fmaf(fr2.w,x2.w,xp);
    xp = fmaf(frB.x,u0,xp); xp = fmaf(frB.y,u1,xp); xp = fmaf(frB.z,u2,xp); xp = fmaf(frB.w,u3,xp);
    __builtin_amdgcn_wave_barrier();   // next step's sxg write must follow this step's reads
    xc = xp;
  };

  // depth-2 prefetch ring, unroll-2 (TT = 50, even)
  float4 g0 = loadg(0);
  float4 g1 = loadg(1);
  for (int t = 0; t < TT; t += 2) {
    body(t, g0);
    if (t + 2 < TT) g0 = loadg(t + 2);
    body(t + 1, g1);
    if (t + 3 < TT) g1 = loadg(t + 3);
  }
}

extern "C" void kernel_launch(void* const* d_in, const int* in_sizes, int n_in,
                              void* d_out, int out_size, void* d_ws, size_t ws_size,
                              hipStream_t stream) {
  (void)in_sizes; (void)n_in; (void)out_size;
  const size_t needF = (size_t)TT * NBB * 52 * sizeof(float);          // 85.2 MB
  const size_t needH = (size_t)TT * NBB * 52 * sizeof(unsigned short); // 42.6 MB
  dim3 grid(NBB / 4), block(64);
  if (d_ws != nullptr && ws_size >= needF) {
    mpc_kernel<0><<<grid, block, 0, stream>>>(d_in[0], d_in[1], d_in[2], d_in[3], d_in[4], d_out, d_ws);
  } else if (d_ws != nullptr && ws_size >= needH) {
    mpc_kernel<1><<<grid, block, 0, stream>>>(d_in[0], d_in[1], d_in[2], d_in[3], d_in[4], d_out, d_ws);
  } else {
    mpc_kernel<2><<<grid, block, 0, stream>>>(d_in[0], d_in[1], d_in[2], d_in[3], d_in[4], d_out, d_ws);
  }
}